// Round 9
// baseline (281.628 us; speedup 1.0000x reference)
//
#include <hip/hip_runtime.h>
#include <hip/hip_bf16.h>

#define B_  4
#define T_  2048
#define C_  1024
#define NH_ 16
#define D_  64
#define BH_ (B_*NH_)   // 64
#define M_  (B_*T_)    // 8192

typedef __attribute__((ext_vector_type(8))) short short8;
typedef __attribute__((ext_vector_type(4))) short short4v;
typedef __attribute__((ext_vector_type(4))) float f32x4;

#define SC2 0.18033688011112043f   // (1/sqrt(64)) * log2(e)

__device__ __forceinline__ ushort f2bf(float f) {
    unsigned u = __float_as_uint(f);
    u += 0x7FFF + ((u >> 16) & 1);   // RNE
    return (ushort)(u >> 16);
}

__device__ __forceinline__ unsigned cvtpk(float lo, float hi) {
    unsigned r;
    asm("v_cvt_pk_bf16_f32 %0, %1, %2" : "=v"(r) : "v"(lo), "v"(hi));
    return r;
}

__device__ __forceinline__ void gload16(const void* g, void* lds) {
    __builtin_amdgcn_global_load_lds(
        (const __attribute__((address_space(1))) void*)g,
        (__attribute__((address_space(3))) void*)lds, 16, 0, 0);
}

// ---------------------------------------------------------------------------
// Prepass: fp32 -> bf16 convert (x) and transpose+convert (weights).
// ---------------------------------------------------------------------------
__global__ __launch_bounds__(256) void convert_x_kernel(
    const float* __restrict__ in, ushort* __restrict__ out, int n8)
{
    const int stride = gridDim.x * 256;
    for (int idx = blockIdx.x * 256 + threadIdx.x; idx < n8; idx += stride) {
        const float* p = in + (size_t)idx * 8;
        f32x4 a = *(const f32x4*)p;
        f32x4 b = *(const f32x4*)(p + 4);
        union { short8 v; ushort u[8]; } pk;
        #pragma unroll
        for (int j = 0; j < 4; ++j) { pk.u[j] = f2bf(a[j]); pk.u[4+j] = f2bf(b[j]); }
        *(short8*)&out[(size_t)idx * 8] = pk.v;
    }
}

// in [K][N] f32  ->  out [N][K] bf16
__global__ __launch_bounds__(256) void transpose_w_kernel(
    const float* __restrict__ in, ushort* __restrict__ out, int K, int N)
{
    __shared__ float t[64][65];
    const int tid = threadIdx.x;
    const int n0 = blockIdx.x * 64;
    const int k0 = blockIdx.y * 64;
    #pragma unroll
    for (int it = 0; it < 16; ++it) {
        const int kr = it*4 + (tid >> 6);
        t[kr][tid & 63] = in[(size_t)(k0 + kr) * N + n0 + (tid & 63)];
    }
    __syncthreads();
    const int nr8 = tid >> 3;          // 0..31
    const int kc0 = (tid & 7) * 8;
    #pragma unroll
    for (int j = 0; j < 2; ++j) {
        const int nr = j*32 + nr8;
        union { short8 v; ushort u[8]; } pk;
        #pragma unroll
        for (int e = 0; e < 8; ++e) pk.u[e] = f2bf(t[kc0 + e][nr]);
        *(short8*)&out[(size_t)(n0 + nr) * K + k0 + kc0] = pk.v;
    }
}

// ---------------------------------------------------------------------------
// 128x256-tile MFMA GEMM, BK=32, 4 waves (2M x 2N), wave tile 64x128
// (4x8 accs -> 43.7 FLOP per LDS byte, above the 40 FLOP/B LDS-BW
// threshold). global_load_lds width-16 staging, double-buffered LDS:
// issue next tile's loads BEFORE computing current tile; single
// __syncthreads per step drains them after the 32 MFMAs.
// MODE 0: scatter epilogue to Q (pre-scaled by SC2) / K / Vt with biases.
// MODE 1: out fp32 + b_proj.
// ---------------------------------------------------------------------------
template<int MODE>
__global__ __launch_bounds__(256) void gemm256_kernel(
    const ushort* __restrict__ A, const ushort* __restrict__ Bt,
    const float* __restrict__ b_attn, const float* __restrict__ bQv,
    const float* __restrict__ bKv,
    ushort* __restrict__ Qb, ushort* __restrict__ Kb, ushort* __restrict__ Vt,
    float* __restrict__ outp, const float* __restrict__ b_proj,
    int K, int N)
{
    __shared__ ushort As[2][128*32];   // 8 KB per buf
    __shared__ ushort Bs[2][256*32];   // 16 KB per buf

    const int tid  = threadIdx.x;
    const int lane = tid & 63;
    const int w    = tid >> 6;
    const int wr   = w >> 1, wc = w & 1;
    const int l16  = lane & 15, lg = lane >> 4;
    const int m0   = blockIdx.x * 128, n0 = blockIdx.y * 256;

    const int srow = lane >> 2;          // 0..15
    const int scol = (lane & 3) * 8;     // k elems
    const ushort* aS = A  + (size_t)(m0 + w*32 + srow) * K + scol;
    const ushort* bS = Bt + (size_t)(n0 + w*64 + srow) * K + scol;

    f32x4 acc[4][8] = {};

    // prologue: stage tile 0 into buf 0 (A: 2 issues, B: 4 issues per wave)
    {
        gload16(aS,                As[0] + w*1024);
        gload16(aS + (size_t)16*K, As[0] + w*1024 + 512);
        gload16(bS,                Bs[0] + w*2048);
        gload16(bS + (size_t)16*K, Bs[0] + w*2048 + 512);
        gload16(bS + (size_t)32*K, Bs[0] + w*2048 + 1024);
        gload16(bS + (size_t)48*K, Bs[0] + w*2048 + 1536);
    }
    __syncthreads();

    int cur = 0;
    for (int k0 = 0; k0 < K; k0 += 32) {
        // issue next tile's loads into the other buffer (overlaps compute)
        if (k0 + 32 < K) {
            const int nx = cur ^ 1;
            const int kn = k0 + 32;
            gload16(aS + kn,                As[nx] + w*1024);
            gload16(aS + (size_t)16*K + kn, As[nx] + w*1024 + 512);
            gload16(bS + kn,                Bs[nx] + w*2048);
            gload16(bS + (size_t)16*K + kn, Bs[nx] + w*2048 + 512);
            gload16(bS + (size_t)32*K + kn, Bs[nx] + w*2048 + 1024);
            gload16(bS + (size_t)48*K + kn, Bs[nx] + w*2048 + 1536);
        }

        short8 af[4], bf[8];
        #pragma unroll
        for (int i = 0; i < 4; ++i)
            af[i] = *(const short8*)&As[cur][(wr*64 + i*16 + l16)*32 + lg*8];
        #pragma unroll
        for (int i = 0; i < 8; ++i)
            bf[i] = *(const short8*)&Bs[cur][(wc*128 + i*16 + l16)*32 + lg*8];

        #pragma unroll
        for (int mi = 0; mi < 4; ++mi)
            #pragma unroll
            for (int ni = 0; ni < 8; ++ni)
                acc[mi][ni] = __builtin_amdgcn_mfma_f32_16x16x32_bf16(
                    af[mi], bf[ni], acc[mi][ni], 0, 0, 0);

        __syncthreads();   // vmcnt(0)+lgkmcnt(0)+barrier: next buf ready
        cur ^= 1;
    }

    #pragma unroll
    for (int ni = 0; ni < 8; ++ni) {
        const int n = n0 + wc*128 + ni*16 + l16;
        if constexpr (MODE == 0) {
            const int sec = n >> 10;      // 0=Q 1=K 2=V
            const int nn  = n & 1023;
            const int h = nn >> 6, d = nn & 63;
            const float ba = b_attn[n];
            #pragma unroll
            for (int mi = 0; mi < 4; ++mi) {
                #pragma unroll
                for (int r = 0; r < 4; ++r) {
                    const int m = m0 + wr*64 + mi*16 + lg*4 + r;
                    const int b = m >> 11, t = m & 2047;
                    float v = acc[mi][ni][r] + ba;
                    if (sec == 0) {
                        v = (v + bQv[nn]) * SC2;  // fold softmax scale into Q
                        Qb[((size_t)(b*NH_ + h)*T_ + t)*D_ + d] = f2bf(v);
                    } else if (sec == 1) {
                        v += bKv[nn];
                        Kb[((size_t)(b*NH_ + h)*T_ + t)*D_ + d] = f2bf(v);
                    } else {
                        Vt[((size_t)(b*NH_ + h)*D_ + d)*T_ + t] = f2bf(v);
                    }
                }
            }
        } else {
            const float bp = b_proj[n];
            #pragma unroll
            for (int mi = 0; mi < 4; ++mi)
                #pragma unroll
                for (int r = 0; r < 4; ++r) {
                    const int m = m0 + wr*64 + mi*16 + lg*4 + r;
                    outp[(size_t)m * N + n] = acc[mi][ni][r] + bp;
                }
        }
    }
}

// ---------------------------------------------------------------------------
// Flash attention v7: online softmax + defer-rescale, 64-q supertile per
// block (one 16-q group per wave) -> grid 2048, uniform p+1 tiles per wave.
// Heavy-first + XCD-chunked. K/V double-buffered in LDS via
// global_load_lds, XOR-swizzled reads.
// ---------------------------------------------------------------------------
__global__ __launch_bounds__(256, 5) void attn_kernel(
    const ushort* __restrict__ Qb, const ushort* __restrict__ Kb,
    const ushort* __restrict__ Vt, ushort* __restrict__ y)
{
    __shared__ char lds[2][16384];   // [buf][ K 8KB | V 8KB ]

    const int tid  = threadIdx.x;
    const int lane = tid & 63;
    const int w    = tid >> 6;
    const int l16  = lane & 15, lg = lane >> 4;
    const int bid  = blockIdx.x;
    const int xcd  = bid & 7;
    const int idx  = bid >> 3;                 // 0..255
    const int bh   = (xcd << 3) | (idx & 7);   // 8 bh per XCD
    const int p    = 31 - (idx >> 3);          // 0..31, heavy supertiles first
    const int b    = bh >> 4, h = bh & 15;
    const size_t kvb = (size_t)bh * T_ * D_;
    const size_t vtb = (size_t)bh * D_ * T_;

    // staging decode (thread-constant): LDS[l] holds tile[r][c] where
    // l = (r*128 + c) ^ ((r&7)<<4)  =>  r = l>>7, c = (l&127)^((r&7)<<4)
    int srow[2], scol[2];
    #pragma unroll
    for (int i = 0; i < 2; ++i) {
        const int l = w*2048 + i*1024 + lane*16;
        const int r = l >> 7;
        const int c = (l & 127) ^ ((r & 7) << 4);
        srow[i] = r; scol[i] = c >> 1;         // elements
    }

    const f32x4 z4 = {0.f, 0.f, 0.f, 0.f};

    const int qw = p * 64 + w * 16;            // wave's 16 q rows

    // Q fragments (B-slot), Q pre-scaled by SC2 at GEMM1
    short8 qf[2];
    #pragma unroll
    for (int c = 0; c < 2; ++c)
        qf[c] = *(const short8*)(Qb + kvb +
                    (size_t)(qw + l16)*D_ + c*32 + lg*8);

    f32x4 o[4] = {};
    float mrow = -1e30f;
    float lrow = 0.f;
    const int nt = p + 1;                      // same for all 4 waves

    // prologue: stage tile 0 into buf 0
    #pragma unroll
    for (int i = 0; i < 2; ++i) {
        gload16(Kb + kvb + (size_t)srow[i]*D_ + scol[i],
                &lds[0][w*2048 + i*1024]);
        gload16(Vt + vtb + (size_t)srow[i]*T_ + scol[i],
                &lds[0][8192 + w*2048 + i*1024]);
    }

    #pragma unroll 1
    for (int t = 0; t < nt; ++t) {
        const int kb = t * 64;
        if (t + 1 < nt) {
            char* Lb = lds[(t + 1) & 1];
            const int kb1 = kb + 64;
            #pragma unroll
            for (int i = 0; i < 2; ++i) {
                gload16(Kb + kvb + (size_t)(kb1 + srow[i])*D_ + scol[i],
                        Lb + w*2048 + i*1024);
                gload16(Vt + vtb + (size_t)srow[i]*T_ + kb1 + scol[i],
                        Lb + 8192 + w*2048 + i*1024);
            }
            asm volatile("s_waitcnt vmcnt(4)" ::: "memory");
        } else {
            asm volatile("s_waitcnt vmcnt(0)" ::: "memory");
        }
        __builtin_amdgcn_s_barrier();

        {
            const char* Lk = lds[t & 1];
            const char* Lv = lds[t & 1] + 8192;

            // ---- S^T = K · Q^T (64 keys x 16 queries) ----
            f32x4 s[4];
            #pragma unroll
            for (int t4 = 0; t4 < 4; ++t4) {
                const int r = t4*16 + l16;
                const int m = (r & 7) << 4;
                const short8 kc0 = *(const short8*)(Lk + r*128 + (( lg*16     ) ^ m));
                const short8 kc1 = *(const short8*)(Lk + r*128 + ((64 + lg*16 ) ^ m));
                s[t4] = __builtin_amdgcn_mfma_f32_16x16x32_bf16(kc0, qf[0], z4,    0, 0, 0);
                s[t4] = __builtin_amdgcn_mfma_f32_16x16x32_bf16(kc1, qf[1], s[t4], 0, 0, 0);
            }

            // ---- online softmax (16 q rows, lane's q = l16) ----
            const bool full = (kb + 63 <= qw);
            float x[4][4];
            #pragma unroll
            for (int t4 = 0; t4 < 4; ++t4)
                #pragma unroll
                for (int r = 0; r < 4; ++r) {
                    float v = s[t4][r];
                    if (!full)
                        v = (kb + t4*16 + lg*4 + r <= qw + l16) ? v : -1e30f;
                    x[t4][r] = v;
                }
            float vm0 = fmaxf(fmaxf(x[0][0], x[0][1]), fmaxf(x[0][2], x[0][3]));
            float vm1 = fmaxf(fmaxf(x[1][0], x[1][1]), fmaxf(x[1][2], x[1][3]));
            float vm2 = fmaxf(fmaxf(x[2][0], x[2][1]), fmaxf(x[2][2], x[2][3]));
            float vm3 = fmaxf(fmaxf(x[3][0], x[3][1]), fmaxf(x[3][2], x[3][3]));
            float vm  = fmaxf(fmaxf(vm0, vm1), fmaxf(vm2, vm3));
            vm = fmaxf(vm, __shfl_xor(vm, 16, 64));
            vm = fmaxf(vm, __shfl_xor(vm, 32, 64));
            const float mn = fmaxf(mrow, vm);
            float rs = 0.f;
            #pragma unroll
            for (int t4 = 0; t4 < 4; ++t4)
                #pragma unroll
                for (int r = 0; r < 4; ++r) {
                    const float pe = __builtin_amdgcn_exp2f(x[t4][r] - mn);
                    x[t4][r] = pe;
                    rs += pe;
                }
            rs += __shfl_xor(rs, 16, 64);
            rs += __shfl_xor(rs, 32, 64);
            if (__all(vm <= mrow)) {
                lrow += rs;                    // alpha == 1 exactly
            } else {
                const float al = __builtin_amdgcn_exp2f(mrow - mn);
                lrow = lrow*al + rs;
                #pragma unroll
                for (int cb = 0; cb < 4; ++cb)
                    #pragma unroll
                    for (int r = 0; r < 4; ++r)
                        o[cb][r] *= al;
            }
            mrow = mn;

            union { unsigned u[4]; short8 v; } p0, p1;
            p0.u[0] = cvtpk(x[0][0], x[0][1]);
            p0.u[1] = cvtpk(x[0][2], x[0][3]);
            p0.u[2] = cvtpk(x[1][0], x[1][1]);
            p0.u[3] = cvtpk(x[1][2], x[1][3]);
            p1.u[0] = cvtpk(x[2][0], x[2][1]);
            p1.u[1] = cvtpk(x[2][2], x[2][3]);
            p1.u[2] = cvtpk(x[3][0], x[3][1]);
            p1.u[3] = cvtpk(x[3][2], x[3][3]);

            // ---- O^T += V^T · P^T (V from swizzled LDS) ----
            #pragma unroll
            for (int cb = 0; cb < 4; ++cb) {
                const int d = cb*16 + l16;
                const int mv = (d & 7) << 4;
                const char* vb = Lv + d*128;
                union { short8 v; short4v hh[2]; } v0, v1;
                v0.hh[0] = *(const short4v*)(vb + ((lg*8     ) ^ mv));
                v0.hh[1] = *(const short4v*)(vb + ((lg*8 + 32) ^ mv));
                v1.hh[0] = *(const short4v*)(vb + ((lg*8 + 64) ^ mv));
                v1.hh[1] = *(const short4v*)(vb + ((lg*8 + 96) ^ mv));
                o[cb] = __builtin_amdgcn_mfma_f32_16x16x32_bf16(v0.v, p0.v, o[cb], 0, 0, 0);
                o[cb] = __builtin_amdgcn_mfma_f32_16x16x32_bf16(v1.v, p1.v, o[cb], 0, 0, 0);
            }
        }
        __builtin_amdgcn_s_barrier();
    }

    // ---- normalize + store y (bf16, [B][T][C]) ----
    {
        const float inv = 1.0f / lrow;
        const int q = qw + l16;
        ushort* yr = y + ((size_t)b*T_ + q)*C_ + h*D_ + lg*4;
        #pragma unroll
        for (int cb = 0; cb < 4; ++cb) {
            union { unsigned u[2]; short4v v; } st;
            st.u[0] = cvtpk(o[cb][0]*inv, o[cb][1]*inv);
            st.u[1] = cvtpk(o[cb][2]*inv, o[cb][3]*inv);
            *(short4v*)(yr + cb*16) = st.v;
        }
    }
}

__global__ void copy_bq_kernel(const float* __restrict__ bQ, float* __restrict__ dst) {
    const int i = blockIdx.x * 256 + threadIdx.x;
    if (i < NH_ * D_) dst[i] = bQ[i];
}

extern "C" void kernel_launch(void* const* d_in, const int* in_sizes, int n_in,
                              void* d_out, int out_size, void* d_ws, size_t ws_size,
                              hipStream_t stream)
{
    const float* x      = (const float*)d_in[0];
    const float* W_attn = (const float*)d_in[1];
    const float* b_attn = (const float*)d_in[2];
    const float* W_proj = (const float*)d_in[3];
    const float* b_proj = (const float*)d_in[4];
    const float* bQ     = (const float*)d_in[5];
    const float* bK     = (const float*)d_in[6];
    float* out = (float*)d_out;

    const size_t HE = (size_t)BH_ * T_ * D_;   // 8M elems
    ushort* Qb = (ushort*)d_ws;
    ushort* Kb = Qb + HE;
    ushort* Vt = Kb + HE;
    ushort* y  = Vt + HE;
    ushort* Wpt = (ushort*)d_ws;               // aliases Qb (dead after attn)

    ushort* Xb  = (ushort*)d_out;              // scratch in d_out (dead before GEMM2)
    ushort* Wat = (ushort*)d_out + (size_t)M_ * C_;

    convert_x_kernel<<<2048, 256, 0, stream>>>(x, Xb, M_*C_/8);
    transpose_w_kernel<<<dim3(3*C_/64, C_/64), 256, 0, stream>>>(W_attn, Wat, C_, 3*C_);

    gemm256_kernel<0><<<dim3(M_/128, 3*C_/256), 256, 0, stream>>>(
        Xb, Wat, b_attn, bQ, bK, Qb, Kb, Vt, nullptr, nullptr, C_, 3*C_);

    attn_kernel<<<2048, 256, 0, stream>>>(Qb, Kb, Vt, y);

    transpose_w_kernel<<<dim3(C_/64, C_/64), 256, 0, stream>>>(W_proj, Wpt, C_, C_);

    gemm256_kernel<1><<<dim3(M_/128, C_/256), 256, 0, stream>>>(
        y, Wpt, nullptr, nullptr, nullptr, nullptr, nullptr, nullptr,
        out, b_proj, C_, C_);

    copy_bq_kernel<<<(NH_*D_ + 255)/256, 256, 0, stream>>>(
        bQ, out + (size_t)M_ * C_);
}

// Round 10
// 208.707 us; speedup vs baseline: 1.3494x; 1.3494x over previous
//
#include <hip/hip_runtime.h>
#include <hip/hip_bf16.h>

#define B_  4
#define T_  2048
#define C_  1024
#define NH_ 16
#define D_  64
#define BH_ (B_*NH_)   // 64
#define M_  (B_*T_)    // 8192

typedef __attribute__((ext_vector_type(8))) short short8;
typedef __attribute__((ext_vector_type(4))) short short4v;
typedef __attribute__((ext_vector_type(4))) float f32x4;

#define SC2 0.18033688011112043f   // (1/sqrt(64)) * log2(e)

__device__ __forceinline__ ushort f2bf(float f) {
    unsigned u = __float_as_uint(f);
    u += 0x7FFF + ((u >> 16) & 1);   // RNE
    return (ushort)(u >> 16);
}

__device__ __forceinline__ unsigned cvtpk(float lo, float hi) {
    unsigned r;
    asm("v_cvt_pk_bf16_f32 %0, %1, %2" : "=v"(r) : "v"(lo), "v"(hi));
    return r;
}

__device__ __forceinline__ void gload16(const void* g, void* lds) {
    __builtin_amdgcn_global_load_lds(
        (const __attribute__((address_space(1))) void*)g,
        (__attribute__((address_space(3))) void*)lds, 16, 0, 0);
}

// ---------------------------------------------------------------------------
// Prepass: fp32 -> bf16 convert (x) and transpose+convert (weights).
// ---------------------------------------------------------------------------
__global__ __launch_bounds__(256) void convert_x_kernel(
    const float* __restrict__ in, ushort* __restrict__ out, int n8)
{
    const int stride = gridDim.x * 256;
    for (int idx = blockIdx.x * 256 + threadIdx.x; idx < n8; idx += stride) {
        const float* p = in + (size_t)idx * 8;
        f32x4 a = *(const f32x4*)p;
        f32x4 b = *(const f32x4*)(p + 4);
        union { short8 v; ushort u[8]; } pk;
        #pragma unroll
        for (int j = 0; j < 4; ++j) { pk.u[j] = f2bf(a[j]); pk.u[4+j] = f2bf(b[j]); }
        *(short8*)&out[(size_t)idx * 8] = pk.v;
    }
}

// in [K][N] f32  ->  out [N][K] bf16
__global__ __launch_bounds__(256) void transpose_w_kernel(
    const float* __restrict__ in, ushort* __restrict__ out, int K, int N)
{
    __shared__ float t[64][65];
    const int tid = threadIdx.x;
    const int n0 = blockIdx.x * 64;
    const int k0 = blockIdx.y * 64;
    #pragma unroll
    for (int it = 0; it < 16; ++it) {
        const int kr = it*4 + (tid >> 6);
        t[kr][tid & 63] = in[(size_t)(k0 + kr) * N + n0 + (tid & 63)];
    }
    __syncthreads();
    const int nr8 = tid >> 3;          // 0..31
    const int kc0 = (tid & 7) * 8;
    #pragma unroll
    for (int j = 0; j < 2; ++j) {
        const int nr = j*32 + nr8;
        union { short8 v; ushort u[8]; } pk;
        #pragma unroll
        for (int e = 0; e < 8; ++e) pk.u[e] = f2bf(t[kc0 + e][nr]);
        *(short8*)&out[(size_t)(n0 + nr) * K + k0 + kc0] = pk.v;
    }
}

// ---------------------------------------------------------------------------
// 128x128-tile MFMA GEMM, BK=32, 4 waves each 64x64, global_load_lds
// width-16 staging. 3-BUFFER COUNTED-VMCNT PIPELINE (T4): two tiles in
// flight at all times; per iter: issue(t+2) -> compute(t) -> vmcnt(4)
// -> s_barrier. vmcnt never drains to 0 in the main loop, so staging
// latency (~1.5 iters of budget) hides under compute.
// Hazards: issue(t+2) writes buf[(t+2)%3], last read in compute(t-1),
// fenced by the end-of-(t-1) barrier. vmcnt(4) (newest 4 = t+2's loads)
// guarantees tile t+1 resident before its compute.
// MODE 0: scatter epilogue to Q (pre-scaled by SC2) / K / Vt with biases.
// MODE 1: out fp32 + b_proj.
// ---------------------------------------------------------------------------
template<int MODE>
__global__ __launch_bounds__(256) void gemm128_kernel(
    const ushort* __restrict__ A, const ushort* __restrict__ Bt,
    const float* __restrict__ b_attn, const float* __restrict__ bQv,
    const float* __restrict__ bKv,
    ushort* __restrict__ Qb, ushort* __restrict__ Kb, ushort* __restrict__ Vt,
    float* __restrict__ outp, const float* __restrict__ b_proj,
    int K, int N)
{
    __shared__ ushort As[3][128*32];   // 8 KB per buf
    __shared__ ushort Bs[3][128*32];   // 8 KB per buf  (total 48 KB)

    const int tid  = threadIdx.x;
    const int lane = tid & 63;
    const int w    = tid >> 6;
    const int wr   = w >> 1, wc = w & 1;
    const int l16  = lane & 15, lg = lane >> 4;
    const int m0   = blockIdx.x * 128, n0 = blockIdx.y * 128;

    const int srow = lane >> 2;          // 0..15
    const int scol = (lane & 3) * 8;     // k elems
    const ushort* aS = A  + (size_t)(m0 + w*32 + srow) * K + scol;
    const ushort* bS = Bt + (size_t)(n0 + w*32 + srow) * K + scol;

    f32x4 acc[4][4] = {};

    const int NT = K >> 5;

    #define STAGE(tk, bi)                                              \
        do {                                                           \
            const int kn_ = (tk) * 32;                                 \
            gload16(aS + kn_,                As[bi] + w*1024);         \
            gload16(aS + (size_t)16*K + kn_, As[bi] + w*1024 + 512);   \
            gload16(bS + kn_,                Bs[bi] + w*1024);         \
            gload16(bS + (size_t)16*K + kn_, Bs[bi] + w*1024 + 512);   \
        } while (0)

    // prologue: tiles 0 and 1 in flight; wait tile 0 only (vmcnt(4))
    STAGE(0, 0);
    STAGE(1, 1);
    asm volatile("s_waitcnt vmcnt(4)" ::: "memory");
    __builtin_amdgcn_s_barrier();

    for (int t = 0; t < NT; ++t) {
        const int cur = t % 3;
        if (t + 2 < NT)
            STAGE(t + 2, (t + 2) % 3);

        short8 af[4], bf[4];
        #pragma unroll
        for (int i = 0; i < 4; ++i) {
            af[i] = *(const short8*)&As[cur][(wr*64 + i*16 + l16)*32 + lg*8];
            bf[i] = *(const short8*)&Bs[cur][(wc*64 + i*16 + l16)*32 + lg*8];
        }
        #pragma unroll
        for (int mi = 0; mi < 4; ++mi)
            #pragma unroll
            for (int ni = 0; ni < 4; ++ni)
                acc[mi][ni] = __builtin_amdgcn_mfma_f32_16x16x32_bf16(
                    af[mi], bf[ni], acc[mi][ni], 0, 0, 0);

        if (t + 1 < NT) {
            if (t + 2 < NT)
                asm volatile("s_waitcnt vmcnt(4)" ::: "memory");  // t+1 ready, t+2 in flight
            else
                asm volatile("s_waitcnt vmcnt(0)" ::: "memory");  // drain for last tile
            __builtin_amdgcn_s_barrier();
        }
    }
    #undef STAGE

    #pragma unroll
    for (int ni = 0; ni < 4; ++ni) {
        const int n = n0 + wc*64 + ni*16 + l16;
        if constexpr (MODE == 0) {
            const int sec = n >> 10;      // 0=Q 1=K 2=V
            const int nn  = n & 1023;
            const int h = nn >> 6, d = nn & 63;
            const float ba = b_attn[n];
            #pragma unroll
            for (int mi = 0; mi < 4; ++mi) {
                #pragma unroll
                for (int r = 0; r < 4; ++r) {
                    const int m = m0 + wr*64 + mi*16 + lg*4 + r;
                    const int b = m >> 11, t = m & 2047;
                    float v = acc[mi][ni][r] + ba;
                    if (sec == 0) {
                        v = (v + bQv[nn]) * SC2;  // fold softmax scale into Q
                        Qb[((size_t)(b*NH_ + h)*T_ + t)*D_ + d] = f2bf(v);
                    } else if (sec == 1) {
                        v += bKv[nn];
                        Kb[((size_t)(b*NH_ + h)*T_ + t)*D_ + d] = f2bf(v);
                    } else {
                        Vt[((size_t)(b*NH_ + h)*D_ + d)*T_ + t] = f2bf(v);
                    }
                }
            }
        } else {
            const float bp = b_proj[n];
            #pragma unroll
            for (int mi = 0; mi < 4; ++mi)
                #pragma unroll
                for (int r = 0; r < 4; ++r) {
                    const int m = m0 + wr*64 + mi*16 + lg*4 + r;
                    outp[(size_t)m * N + n] = acc[mi][ni][r] + bp;
                }
        }
    }
}

// ---------------------------------------------------------------------------
// Flash attention v7: online softmax + defer-rescale, 64-q supertile per
// block (one 16-q group per wave) -> grid 2048, uniform p+1 tiles per wave.
// Heavy-first + XCD-chunked. K/V double-buffered in LDS via
// global_load_lds, XOR-swizzled reads.
// ---------------------------------------------------------------------------
__global__ __launch_bounds__(256, 5) void attn_kernel(
    const ushort* __restrict__ Qb, const ushort* __restrict__ Kb,
    const ushort* __restrict__ Vt, ushort* __restrict__ y)
{
    __shared__ char lds[2][16384];   // [buf][ K 8KB | V 8KB ]

    const int tid  = threadIdx.x;
    const int lane = tid & 63;
    const int w    = tid >> 6;
    const int l16  = lane & 15, lg = lane >> 4;
    const int bid  = blockIdx.x;
    const int xcd  = bid & 7;
    const int idx  = bid >> 3;                 // 0..255
    const int bh   = (xcd << 3) | (idx & 7);   // 8 bh per XCD
    const int p    = 31 - (idx >> 3);          // 0..31, heavy supertiles first
    const int b    = bh >> 4, h = bh & 15;
    const size_t kvb = (size_t)bh * T_ * D_;
    const size_t vtb = (size_t)bh * D_ * T_;

    // staging decode (thread-constant): LDS[l] holds tile[r][c] where
    // l = (r*128 + c) ^ ((r&7)<<4)  =>  r = l>>7, c = (l&127)^((r&7)<<4)
    int srow[2], scol[2];
    #pragma unroll
    for (int i = 0; i < 2; ++i) {
        const int l = w*2048 + i*1024 + lane*16;
        const int r = l >> 7;
        const int c = (l & 127) ^ ((r & 7) << 4);
        srow[i] = r; scol[i] = c >> 1;         // elements
    }

    const f32x4 z4 = {0.f, 0.f, 0.f, 0.f};

    const int qw = p * 64 + w * 16;            // wave's 16 q rows

    // Q fragments (B-slot), Q pre-scaled by SC2 at GEMM1
    short8 qf[2];
    #pragma unroll
    for (int c = 0; c < 2; ++c)
        qf[c] = *(const short8*)(Qb + kvb +
                    (size_t)(qw + l16)*D_ + c*32 + lg*8);

    f32x4 o[4] = {};
    float mrow = -1e30f;
    float lrow = 0.f;
    const int nt = p + 1;                      // same for all 4 waves

    // prologue: stage tile 0 into buf 0
    #pragma unroll
    for (int i = 0; i < 2; ++i) {
        gload16(Kb + kvb + (size_t)srow[i]*D_ + scol[i],
                &lds[0][w*2048 + i*1024]);
        gload16(Vt + vtb + (size_t)srow[i]*T_ + scol[i],
                &lds[0][8192 + w*2048 + i*1024]);
    }

    #pragma unroll 1
    for (int t = 0; t < nt; ++t) {
        const int kb = t * 64;
        if (t + 1 < nt) {
            char* Lb = lds[(t + 1) & 1];
            const int kb1 = kb + 64;
            #pragma unroll
            for (int i = 0; i < 2; ++i) {
                gload16(Kb + kvb + (size_t)(kb1 + srow[i])*D_ + scol[i],
                        Lb + w*2048 + i*1024);
                gload16(Vt + vtb + (size_t)srow[i]*T_ + kb1 + scol[i],
                        Lb + 8192 + w*2048 + i*1024);
            }
            asm volatile("s_waitcnt vmcnt(4)" ::: "memory");
        } else {
            asm volatile("s_waitcnt vmcnt(0)" ::: "memory");
        }
        __builtin_amdgcn_s_barrier();

        {
            const char* Lk = lds[t & 1];
            const char* Lv = lds[t & 1] + 8192;

            // ---- S^T = K · Q^T (64 keys x 16 queries) ----
            f32x4 s[4];
            #pragma unroll
            for (int t4 = 0; t4 < 4; ++t4) {
                const int r = t4*16 + l16;
                const int m = (r & 7) << 4;
                const short8 kc0 = *(const short8*)(Lk + r*128 + (( lg*16     ) ^ m));
                const short8 kc1 = *(const short8*)(Lk + r*128 + ((64 + lg*16 ) ^ m));
                s[t4] = __builtin_amdgcn_mfma_f32_16x16x32_bf16(kc0, qf[0], z4,    0, 0, 0);
                s[t4] = __builtin_amdgcn_mfma_f32_16x16x32_bf16(kc1, qf[1], s[t4], 0, 0, 0);
            }

            // ---- online softmax (16 q rows, lane's q = l16) ----
            const bool full = (kb + 63 <= qw);
            float x[4][4];
            #pragma unroll
            for (int t4 = 0; t4 < 4; ++t4)
                #pragma unroll
                for (int r = 0; r < 4; ++r) {
                    float v = s[t4][r];
                    if (!full)
                        v = (kb + t4*16 + lg*4 + r <= qw + l16) ? v : -1e30f;
                    x[t4][r] = v;
                }
            float vm0 = fmaxf(fmaxf(x[0][0], x[0][1]), fmaxf(x[0][2], x[0][3]));
            float vm1 = fmaxf(fmaxf(x[1][0], x[1][1]), fmaxf(x[1][2], x[1][3]));
            float vm2 = fmaxf(fmaxf(x[2][0], x[2][1]), fmaxf(x[2][2], x[2][3]));
            float vm3 = fmaxf(fmaxf(x[3][0], x[3][1]), fmaxf(x[3][2], x[3][3]));
            float vm  = fmaxf(fmaxf(vm0, vm1), fmaxf(vm2, vm3));
            vm = fmaxf(vm, __shfl_xor(vm, 16, 64));
            vm = fmaxf(vm, __shfl_xor(vm, 32, 64));
            const float mn = fmaxf(mrow, vm);
            float rs = 0.f;
            #pragma unroll
            for (int t4 = 0; t4 < 4; ++t4)
                #pragma unroll
                for (int r = 0; r < 4; ++r) {
                    const float pe = __builtin_amdgcn_exp2f(x[t4][r] - mn);
                    x[t4][r] = pe;
                    rs += pe;
                }
            rs += __shfl_xor(rs, 16, 64);
            rs += __shfl_xor(rs, 32, 64);
            if (__all(vm <= mrow)) {
                lrow += rs;                    // alpha == 1 exactly
            } else {
                const float al = __builtin_amdgcn_exp2f(mrow - mn);
                lrow = lrow*al + rs;
                #pragma unroll
                for (int cb = 0; cb < 4; ++cb)
                    #pragma unroll
                    for (int r = 0; r < 4; ++r)
                        o[cb][r] *= al;
            }
            mrow = mn;

            union { unsigned u[4]; short8 v; } p0, p1;
            p0.u[0] = cvtpk(x[0][0], x[0][1]);
            p0.u[1] = cvtpk(x[0][2], x[0][3]);
            p0.u[2] = cvtpk(x[1][0], x[1][1]);
            p0.u[3] = cvtpk(x[1][2], x[1][3]);
            p1.u[0] = cvtpk(x[2][0], x[2][1]);
            p1.u[1] = cvtpk(x[2][2], x[2][3]);
            p1.u[2] = cvtpk(x[3][0], x[3][1]);
            p1.u[3] = cvtpk(x[3][2], x[3][3]);

            // ---- O^T += V^T · P^T (V from swizzled LDS) ----
            #pragma unroll
            for (int cb = 0; cb < 4; ++cb) {
                const int d = cb*16 + l16;
                const int mv = (d & 7) << 4;
                const char* vb = Lv + d*128;
                union { short8 v; short4v hh[2]; } v0, v1;
                v0.hh[0] = *(const short4v*)(vb + ((lg*8     ) ^ mv));
                v0.hh[1] = *(const short4v*)(vb + ((lg*8 + 32) ^ mv));
                v1.hh[0] = *(const short4v*)(vb + ((lg*8 + 64) ^ mv));
                v1.hh[1] = *(const short4v*)(vb + ((lg*8 + 96) ^ mv));
                o[cb] = __builtin_amdgcn_mfma_f32_16x16x32_bf16(v0.v, p0.v, o[cb], 0, 0, 0);
                o[cb] = __builtin_amdgcn_mfma_f32_16x16x32_bf16(v1.v, p1.v, o[cb], 0, 0, 0);
            }
        }
        __builtin_amdgcn_s_barrier();
    }

    // ---- normalize + store y (bf16, [B][T][C]) ----
    {
        const float inv = 1.0f / lrow;
        const int q = qw + l16;
        ushort* yr = y + ((size_t)b*T_ + q)*C_ + h*D_ + lg*4;
        #pragma unroll
        for (int cb = 0; cb < 4; ++cb) {
            union { unsigned u[2]; short4v v; } st;
            st.u[0] = cvtpk(o[cb][0]*inv, o[cb][1]*inv);
            st.u[1] = cvtpk(o[cb][2]*inv, o[cb][3]*inv);
            *(short4v*)(yr + cb*16) = st.v;
        }
    }
}

__global__ void copy_bq_kernel(const float* __restrict__ bQ, float* __restrict__ dst) {
    const int i = blockIdx.x * 256 + threadIdx.x;
    if (i < NH_ * D_) dst[i] = bQ[i];
}

extern "C" void kernel_launch(void* const* d_in, const int* in_sizes, int n_in,
                              void* d_out, int out_size, void* d_ws, size_t ws_size,
                              hipStream_t stream)
{
    const float* x      = (const float*)d_in[0];
    const float* W_attn = (const float*)d_in[1];
    const float* b_attn = (const float*)d_in[2];
    const float* W_proj = (const float*)d_in[3];
    const float* b_proj = (const float*)d_in[4];
    const float* bQ     = (const float*)d_in[5];
    const float* bK     = (const float*)d_in[6];
    float* out = (float*)d_out;

    const size_t HE = (size_t)BH_ * T_ * D_;   // 8M elems
    ushort* Qb = (ushort*)d_ws;
    ushort* Kb = Qb + HE;
    ushort* Vt = Kb + HE;
    ushort* y  = Vt + HE;
    ushort* Wpt = (ushort*)d_ws;               // aliases Qb (dead after attn)

    ushort* Xb  = (ushort*)d_out;              // scratch in d_out (dead before GEMM2)
    ushort* Wat = (ushort*)d_out + (size_t)M_ * C_;

    convert_x_kernel<<<2048, 256, 0, stream>>>(x, Xb, M_*C_/8);
    transpose_w_kernel<<<dim3(3*C_/64, C_/64), 256, 0, stream>>>(W_attn, Wat, C_, 3*C_);

    gemm128_kernel<0><<<dim3(M_/128, 3*C_/128), 256, 0, stream>>>(
        Xb, Wat, b_attn, bQ, bK, Qb, Kb, Vt, nullptr, nullptr, C_, 3*C_);

    attn_kernel<<<2048, 256, 0, stream>>>(Qb, Kb, Vt, y);

    transpose_w_kernel<<<dim3(C_/64, C_/64), 256, 0, stream>>>(W_proj, Wpt, C_, C_);

    gemm128_kernel<1><<<dim3(M_/128, C_/128), 256, 0, stream>>>(
        y, Wpt, nullptr, nullptr, nullptr, nullptr, nullptr, nullptr,
        out, b_proj, C_, C_);

    copy_bq_kernel<<<(NH_*D_ + 255)/256, 256, 0, stream>>>(
        bQ, out + (size_t)M_ * C_);
}

// Round 11
// 206.252 us; speedup vs baseline: 1.3655x; 1.0119x over previous
//
#include <hip/hip_runtime.h>
#include <hip/hip_bf16.h>

#define B_  4
#define T_  2048
#define C_  1024
#define NH_ 16
#define D_  64
#define BH_ (B_*NH_)   // 64
#define M_  (B_*T_)    // 8192

typedef __attribute__((ext_vector_type(8))) short short8;
typedef __attribute__((ext_vector_type(4))) short short4v;
typedef __attribute__((ext_vector_type(4))) float f32x4;

#define SC2 0.18033688011112043f   // (1/sqrt(64)) * log2(e)

__device__ __forceinline__ ushort f2bf(float f) {
    unsigned u = __float_as_uint(f);
    u += 0x7FFF + ((u >> 16) & 1);   // RNE
    return (ushort)(u >> 16);
}

__device__ __forceinline__ unsigned cvtpk(float lo, float hi) {
    unsigned r;
    asm("v_cvt_pk_bf16_f32 %0, %1, %2" : "=v"(r) : "v"(lo), "v"(hi));
    return r;
}

__device__ __forceinline__ void gload16(const void* g, void* lds) {
    __builtin_amdgcn_global_load_lds(
        (const __attribute__((address_space(1))) void*)g,
        (__attribute__((address_space(3))) void*)lds, 16, 0, 0);
}

// ---------------------------------------------------------------------------
// Prepass: fp32 -> bf16 convert (x) and transpose+convert (weights).
// ---------------------------------------------------------------------------
__global__ __launch_bounds__(256) void convert_x_kernel(
    const float* __restrict__ in, ushort* __restrict__ out, int n8)
{
    const int stride = gridDim.x * 256;
    for (int idx = blockIdx.x * 256 + threadIdx.x; idx < n8; idx += stride) {
        const float* p = in + (size_t)idx * 8;
        f32x4 a = *(const f32x4*)p;
        f32x4 b = *(const f32x4*)(p + 4);
        union { short8 v; ushort u[8]; } pk;
        #pragma unroll
        for (int j = 0; j < 4; ++j) { pk.u[j] = f2bf(a[j]); pk.u[4+j] = f2bf(b[j]); }
        *(short8*)&out[(size_t)idx * 8] = pk.v;
    }
}

// in [K][N] f32  ->  out [N][K] bf16
__global__ __launch_bounds__(256) void transpose_w_kernel(
    const float* __restrict__ in, ushort* __restrict__ out, int K, int N)
{
    __shared__ float t[64][65];
    const int tid = threadIdx.x;
    const int n0 = blockIdx.x * 64;
    const int k0 = blockIdx.y * 64;
    #pragma unroll
    for (int it = 0; it < 16; ++it) {
        const int kr = it*4 + (tid >> 6);
        t[kr][tid & 63] = in[(size_t)(k0 + kr) * N + n0 + (tid & 63)];
    }
    __syncthreads();
    const int nr8 = tid >> 3;          // 0..31
    const int kc0 = (tid & 7) * 8;
    #pragma unroll
    for (int j = 0; j < 2; ++j) {
        const int nr = j*32 + nr8;
        union { short8 v; ushort u[8]; } pk;
        #pragma unroll
        for (int e = 0; e < 8; ++e) pk.u[e] = f2bf(t[kc0 + e][nr]);
        *(short8*)&out[(size_t)(n0 + nr) * K + k0 + kc0] = pk.v;
    }
}

// ---------------------------------------------------------------------------
// 8-phase-style GEMM (T2+T3+T4+T5): tile 128(M)x256(N), 8 waves (2Mx4N),
// wave-tile 64x64, BK=64, 3 LDS buffers (144 KB), counted vmcnt(6).
// LDS rows are 128 B -> XOR-swizzle c ^= (row&7)<<4 on ds_read addresses,
// with the inverse swizzle applied to the per-lane GLOBAL source address
// (global_load_lds writes linearly: LDS linear slot <- swizzled source).
// Per K-tile: 2 sub-phases, each {ds_read + 3 gload_lds -> barrier ->
// lgkmcnt(0)+sched_barrier -> setprio(1) -> 16 MFMA -> setprio(0) -> barrier}.
// MODE 0: scatter epilogue to Q (pre-scaled by SC2) / K / Vt with biases.
// MODE 1: out fp32 + b_proj.
// ---------------------------------------------------------------------------
#define A_BUF 8192    // 128*64 ushorts
#define B_BUF 16384   // 256*64 ushorts

template<int MODE>
__global__ __launch_bounds__(512) void gemm8p_kernel(
    const ushort* __restrict__ A, const ushort* __restrict__ Bt,
    const float* __restrict__ b_attn, const float* __restrict__ bQv,
    const float* __restrict__ bKv,
    ushort* __restrict__ Qb, ushort* __restrict__ Kb, ushort* __restrict__ Vt,
    float* __restrict__ outp, const float* __restrict__ b_proj,
    int K, int N)
{
    __shared__ ushort lds[3*A_BUF + 3*B_BUF];   // 144 KB

    const int tid  = threadIdx.x;
    const int lane = tid & 63;
    const int w    = tid >> 6;        // 0..7
    const int wr   = w >> 2;          // 0..1 (M)
    const int wc   = w & 3;           // 0..3 (N)
    const int l16  = lane & 15, lg = lane >> 4;
    const int m0   = blockIdx.x * 128, n0 = blockIdx.y * 256;

    // swizzled ds_read column offsets (ushorts), kh = 0,1
    const int csw0 = (((0*64) + lg*16) ^ ((l16 & 7) << 4)) >> 1;
    const int csw1 = (((1*64) + lg*16) ^ ((l16 & 7) << 4)) >> 1;

    // staging: each gload16 covers 8 rows x 128B; lane -> row lane>>3,
    // 16B slot lane&7. Inverse-swizzled global column (elements):
    const int gcol = 8 * ((lane & 7) ^ (lane >> 3));
    const ushort* aSrc = A  + (size_t)(m0 + w*16 + (lane >> 3)) * K + gcol;
    const ushort* bSrc = Bt + (size_t)(n0 + w*32 + (lane >> 3)) * K + gcol;

    const int NT = K >> 6;   // 16

    #define STG_A(tk, buf)                                                  \
        do { const size_t kk_ = (size_t)(tk) * 64;                          \
             ushort* d_ = lds + (buf)*A_BUF;                                \
             gload16(aSrc + kk_,               d_ + (w*16 + 0)*64);         \
             gload16(aSrc + (size_t)8*K + kk_, d_ + (w*16 + 8)*64); } while(0)
    #define STG_B1(tk, buf)                                                 \
        do { const size_t kk_ = (size_t)(tk) * 64;                          \
             ushort* d_ = lds + 3*A_BUF + (buf)*B_BUF;                      \
             gload16(bSrc + kk_,               d_ + (w*32 + 0)*64); } while(0)
    #define STG_B3(tk, buf)                                                 \
        do { const size_t kk_ = (size_t)(tk) * 64;                          \
             ushort* d_ = lds + 3*A_BUF + (buf)*B_BUF;                      \
             gload16(bSrc + (size_t)8*K  + kk_, d_ + (w*32 + 8)*64);        \
             gload16(bSrc + (size_t)16*K + kk_, d_ + (w*32 + 16)*64);       \
             gload16(bSrc + (size_t)24*K + kk_, d_ + (w*32 + 24)*64); } while(0)

    f32x4 acc[4][4] = {};

    // prologue: tiles 0,1 fully staged; wait tile 0 (newest 6 = tile 1's)
    STG_A(0, 0); STG_B1(0, 0); STG_B3(0, 0);
    STG_A(1, 1); STG_B1(1, 1); STG_B3(1, 1);
    asm volatile("s_waitcnt vmcnt(6)" ::: "memory");
    __builtin_amdgcn_s_barrier();

    #pragma unroll 1
    for (int t = 0; t < NT; ++t) {
        const int cur = t % 3;
        const int nxb = (t + 2) % 3;
        const bool st = (t + 2 < NT);
        const ushort* Ab = lds + cur*A_BUF;
        const ushort* Bb = lds + 3*A_BUF + cur*B_BUF;

        // ================= sub-phase A (mi = 0,1) =================
        short8 af0[2], af1[2], bf[4][2];
        {
            const int rA0 = (wr*64 +  0 + l16) * 64;
            const int rA1 = (wr*64 + 16 + l16) * 64;
            af0[0] = *(const short8*)&Ab[rA0 + csw0];
            af0[1] = *(const short8*)&Ab[rA0 + csw1];
            af1[0] = *(const short8*)&Ab[rA1 + csw0];
            af1[1] = *(const short8*)&Ab[rA1 + csw1];
            #pragma unroll
            for (int ni = 0; ni < 4; ++ni) {
                const int rB = (wc*64 + ni*16 + l16) * 64;
                bf[ni][0] = *(const short8*)&Bb[rB + csw0];
                bf[ni][1] = *(const short8*)&Bb[rB + csw1];
            }
        }
        if (st) { STG_A(t + 2, nxb); STG_B1(t + 2, nxb); }
        __builtin_amdgcn_s_barrier();
        asm volatile("s_waitcnt lgkmcnt(0)" ::: "memory");
        __builtin_amdgcn_sched_barrier(0);
        __builtin_amdgcn_s_setprio(1);
        #pragma unroll
        for (int ni = 0; ni < 4; ++ni) {
            acc[0][ni] = __builtin_amdgcn_mfma_f32_16x16x32_bf16(af0[0], bf[ni][0], acc[0][ni], 0, 0, 0);
            acc[0][ni] = __builtin_amdgcn_mfma_f32_16x16x32_bf16(af0[1], bf[ni][1], acc[0][ni], 0, 0, 0);
            acc[1][ni] = __builtin_amdgcn_mfma_f32_16x16x32_bf16(af1[0], bf[ni][0], acc[1][ni], 0, 0, 0);
            acc[1][ni] = __builtin_amdgcn_mfma_f32_16x16x32_bf16(af1[1], bf[ni][1], acc[1][ni], 0, 0, 0);
        }
        __builtin_amdgcn_s_setprio(0);
        __builtin_amdgcn_s_barrier();

        // ================= sub-phase B (mi = 2,3) =================
        short8 af2[2], af3[2];
        {
            const int rA2 = (wr*64 + 32 + l16) * 64;
            const int rA3 = (wr*64 + 48 + l16) * 64;
            af2[0] = *(const short8*)&Ab[rA2 + csw0];
            af2[1] = *(const short8*)&Ab[rA2 + csw1];
            af3[0] = *(const short8*)&Ab[rA3 + csw0];
            af3[1] = *(const short8*)&Ab[rA3 + csw1];
        }
        if (st) STG_B3(t + 2, nxb);
        __builtin_amdgcn_s_barrier();
        asm volatile("s_waitcnt lgkmcnt(0)" ::: "memory");
        __builtin_amdgcn_sched_barrier(0);
        __builtin_amdgcn_s_setprio(1);
        #pragma unroll
        for (int ni = 0; ni < 4; ++ni) {
            acc[2][ni] = __builtin_amdgcn_mfma_f32_16x16x32_bf16(af2[0], bf[ni][0], acc[2][ni], 0, 0, 0);
            acc[2][ni] = __builtin_amdgcn_mfma_f32_16x16x32_bf16(af2[1], bf[ni][1], acc[2][ni], 0, 0, 0);
            acc[3][ni] = __builtin_amdgcn_mfma_f32_16x16x32_bf16(af3[0], bf[ni][0], acc[3][ni], 0, 0, 0);
            acc[3][ni] = __builtin_amdgcn_mfma_f32_16x16x32_bf16(af3[1], bf[ni][1], acc[3][ni], 0, 0, 0);
        }
        __builtin_amdgcn_s_setprio(0);
        if (st) asm volatile("s_waitcnt vmcnt(6)" ::: "memory");
        else    asm volatile("s_waitcnt vmcnt(0)" ::: "memory");
        __builtin_amdgcn_s_barrier();
    }
    #undef STG_A
    #undef STG_B1
    #undef STG_B3

    // ---- epilogue ----
    #pragma unroll
    for (int ni = 0; ni < 4; ++ni) {
        const int n = n0 + wc*64 + ni*16 + l16;
        if constexpr (MODE == 0) {
            const int sec = n >> 10;      // 0=Q 1=K 2=V
            const int nn  = n & 1023;
            const int h = nn >> 6, d = nn & 63;
            const float ba = b_attn[n];
            #pragma unroll
            for (int mi = 0; mi < 4; ++mi) {
                #pragma unroll
                for (int r = 0; r < 4; ++r) {
                    const int m = m0 + wr*64 + mi*16 + lg*4 + r;
                    const int b = m >> 11, tt = m & 2047;
                    float v = acc[mi][ni][r] + ba;
                    if (sec == 0) {
                        v = (v + bQv[nn]) * SC2;  // fold softmax scale into Q
                        Qb[((size_t)(b*NH_ + h)*T_ + tt)*D_ + d] = f2bf(v);
                    } else if (sec == 1) {
                        v += bKv[nn];
                        Kb[((size_t)(b*NH_ + h)*T_ + tt)*D_ + d] = f2bf(v);
                    } else {
                        Vt[((size_t)(b*NH_ + h)*D_ + d)*T_ + tt] = f2bf(v);
                    }
                }
            }
        } else {
            const float bp = b_proj[n];
            #pragma unroll
            for (int mi = 0; mi < 4; ++mi)
                #pragma unroll
                for (int r = 0; r < 4; ++r) {
                    const int m = m0 + wr*64 + mi*16 + lg*4 + r;
                    outp[(size_t)m * N + n] = acc[mi][ni][r] + bp;
                }
        }
    }
}

// ---------------------------------------------------------------------------
// Flash attention v7: online softmax + defer-rescale, 64-q supertile per
// block (one 16-q group per wave) -> grid 2048, uniform p+1 tiles per wave.
// Heavy-first + XCD-chunked. K/V double-buffered in LDS via
// global_load_lds, XOR-swizzled reads.
// ---------------------------------------------------------------------------
__global__ __launch_bounds__(256, 5) void attn_kernel(
    const ushort* __restrict__ Qb, const ushort* __restrict__ Kb,
    const ushort* __restrict__ Vt, ushort* __restrict__ y)
{
    __shared__ char lds[2][16384];   // [buf][ K 8KB | V 8KB ]

    const int tid  = threadIdx.x;
    const int lane = tid & 63;
    const int w    = tid >> 6;
    const int l16  = lane & 15, lg = lane >> 4;
    const int bid  = blockIdx.x;
    const int xcd  = bid & 7;
    const int idx  = bid >> 3;                 // 0..255
    const int bh   = (xcd << 3) | (idx & 7);   // 8 bh per XCD
    const int p    = 31 - (idx >> 3);          // 0..31, heavy supertiles first
    const int b    = bh >> 4, h = bh & 15;
    const size_t kvb = (size_t)bh * T_ * D_;
    const size_t vtb = (size_t)bh * D_ * T_;

    int srow[2], scol[2];
    #pragma unroll
    for (int i = 0; i < 2; ++i) {
        const int l = w*2048 + i*1024 + lane*16;
        const int r = l >> 7;
        const int c = (l & 127) ^ ((r & 7) << 4);
        srow[i] = r; scol[i] = c >> 1;         // elements
    }

    const f32x4 z4 = {0.f, 0.f, 0.f, 0.f};

    const int qw = p * 64 + w * 16;            // wave's 16 q rows

    short8 qf[2];
    #pragma unroll
    for (int c = 0; c < 2; ++c)
        qf[c] = *(const short8*)(Qb + kvb +
                    (size_t)(qw + l16)*D_ + c*32 + lg*8);

    f32x4 o[4] = {};
    float mrow = -1e30f;
    float lrow = 0.f;
    const int nt = p + 1;                      // same for all 4 waves

    #pragma unroll
    for (int i = 0; i < 2; ++i) {
        gload16(Kb + kvb + (size_t)srow[i]*D_ + scol[i],
                &lds[0][w*2048 + i*1024]);
        gload16(Vt + vtb + (size_t)srow[i]*T_ + scol[i],
                &lds[0][8192 + w*2048 + i*1024]);
    }

    #pragma unroll 1
    for (int t = 0; t < nt; ++t) {
        const int kb = t * 64;
        if (t + 1 < nt) {
            char* Lb = lds[(t + 1) & 1];
            const int kb1 = kb + 64;
            #pragma unroll
            for (int i = 0; i < 2; ++i) {
                gload16(Kb + kvb + (size_t)(kb1 + srow[i])*D_ + scol[i],
                        Lb + w*2048 + i*1024);
                gload16(Vt + vtb + (size_t)srow[i]*T_ + kb1 + scol[i],
                        Lb + 8192 + w*2048 + i*1024);
            }
            asm volatile("s_waitcnt vmcnt(4)" ::: "memory");
        } else {
            asm volatile("s_waitcnt vmcnt(0)" ::: "memory");
        }
        __builtin_amdgcn_s_barrier();

        {
            const char* Lk = lds[t & 1];
            const char* Lv = lds[t & 1] + 8192;

            f32x4 s[4];
            #pragma unroll
            for (int t4 = 0; t4 < 4; ++t4) {
                const int r = t4*16 + l16;
                const int m = (r & 7) << 4;
                const short8 kc0 = *(const short8*)(Lk + r*128 + (( lg*16     ) ^ m));
                const short8 kc1 = *(const short8*)(Lk + r*128 + ((64 + lg*16 ) ^ m));
                s[t4] = __builtin_amdgcn_mfma_f32_16x16x32_bf16(kc0, qf[0], z4,    0, 0, 0);
                s[t4] = __builtin_amdgcn_mfma_f32_16x16x32_bf16(kc1, qf[1], s[t4], 0, 0, 0);
            }

            const bool full = (kb + 63 <= qw);
            float x[4][4];
            #pragma unroll
            for (int t4 = 0; t4 < 4; ++t4)
                #pragma unroll
                for (int r = 0; r < 4; ++r) {
                    float v = s[t4][r];
                    if (!full)
                        v = (kb + t4*16 + lg*4 + r <= qw + l16) ? v : -1e30f;
                    x[t4][r] = v;
                }
            float vm0 = fmaxf(fmaxf(x[0][0], x[0][1]), fmaxf(x[0][2], x[0][3]));
            float vm1 = fmaxf(fmaxf(x[1][0], x[1][1]), fmaxf(x[1][2], x[1][3]));
            float vm2 = fmaxf(fmaxf(x[2][0], x[2][1]), fmaxf(x[2][2], x[2][3]));
            float vm3 = fmaxf(fmaxf(x[3][0], x[3][1]), fmaxf(x[3][2], x[3][3]));
            float vm  = fmaxf(fmaxf(vm0, vm1), fmaxf(vm2, vm3));
            vm = fmaxf(vm, __shfl_xor(vm, 16, 64));
            vm = fmaxf(vm, __shfl_xor(vm, 32, 64));
            const float mn = fmaxf(mrow, vm);
            float rs = 0.f;
            #pragma unroll
            for (int t4 = 0; t4 < 4; ++t4)
                #pragma unroll
                for (int r = 0; r < 4; ++r) {
                    const float pe = __builtin_amdgcn_exp2f(x[t4][r] - mn);
                    x[t4][r] = pe;
                    rs += pe;
                }
            rs += __shfl_xor(rs, 16, 64);
            rs += __shfl_xor(rs, 32, 64);
            if (__all(vm <= mrow)) {
                lrow += rs;                    // alpha == 1 exactly
            } else {
                const float al = __builtin_amdgcn_exp2f(mrow - mn);
                lrow = lrow*al + rs;
                #pragma unroll
                for (int cb = 0; cb < 4; ++cb)
                    #pragma unroll
                    for (int r = 0; r < 4; ++r)
                        o[cb][r] *= al;
            }
            mrow = mn;

            union { unsigned u[4]; short8 v; } p0, p1;
            p0.u[0] = cvtpk(x[0][0], x[0][1]);
            p0.u[1] = cvtpk(x[0][2], x[0][3]);
            p0.u[2] = cvtpk(x[1][0], x[1][1]);
            p0.u[3] = cvtpk(x[1][2], x[1][3]);
            p1.u[0] = cvtpk(x[2][0], x[2][1]);
            p1.u[1] = cvtpk(x[2][2], x[2][3]);
            p1.u[2] = cvtpk(x[3][0], x[3][1]);
            p1.u[3] = cvtpk(x[3][2], x[3][3]);

            #pragma unroll
            for (int cb = 0; cb < 4; ++cb) {
                const int d = cb*16 + l16;
                const int mv = (d & 7) << 4;
                const char* vb = Lv + d*128;
                union { short8 v; short4v hh[2]; } v0, v1;
                v0.hh[0] = *(const short4v*)(vb + ((lg*8     ) ^ mv));
                v0.hh[1] = *(const short4v*)(vb + ((lg*8 + 32) ^ mv));
                v1.hh[0] = *(const short4v*)(vb + ((lg*8 + 64) ^ mv));
                v1.hh[1] = *(const short4v*)(vb + ((lg*8 + 96) ^ mv));
                o[cb] = __builtin_amdgcn_mfma_f32_16x16x32_bf16(v0.v, p0.v, o[cb], 0, 0, 0);
                o[cb] = __builtin_amdgcn_mfma_f32_16x16x32_bf16(v1.v, p1.v, o[cb], 0, 0, 0);
            }
        }
        __builtin_amdgcn_s_barrier();
    }

    {
        const float inv = 1.0f / lrow;
        const int q = qw + l16;
        ushort* yr = y + ((size_t)b*T_ + q)*C_ + h*D_ + lg*4;
        #pragma unroll
        for (int cb = 0; cb < 4; ++cb) {
            union { unsigned u[2]; short4v v; } st;
            st.u[0] = cvtpk(o[cb][0]*inv, o[cb][1]*inv);
            st.u[1] = cvtpk(o[cb][2]*inv, o[cb][3]*inv);
            *(short4v*)(yr + cb*16) = st.v;
        }
    }
}

__global__ void copy_bq_kernel(const float* __restrict__ bQ, float* __restrict__ dst) {
    const int i = blockIdx.x * 256 + threadIdx.x;
    if (i < NH_ * D_) dst[i] = bQ[i];
}

extern "C" void kernel_launch(void* const* d_in, const int* in_sizes, int n_in,
                              void* d_out, int out_size, void* d_ws, size_t ws_size,
                              hipStream_t stream)
{
    const float* x      = (const float*)d_in[0];
    const float* W_attn = (const float*)d_in[1];
    const float* b_attn = (const float*)d_in[2];
    const float* W_proj = (const float*)d_in[3];
    const float* b_proj = (const float*)d_in[4];
    const float* bQ     = (const float*)d_in[5];
    const float* bK     = (const float*)d_in[6];
    float* out = (float*)d_out;

    const size_t HE = (size_t)BH_ * T_ * D_;   // 8M elems
    ushort* Qb = (ushort*)d_ws;
    ushort* Kb = Qb + HE;
    ushort* Vt = Kb + HE;
    ushort* y  = Vt + HE;
    ushort* Wpt = (ushort*)d_ws;               // aliases Qb (dead after attn)

    ushort* Xb  = (ushort*)d_out;              // scratch in d_out (dead before GEMM2)
    ushort* Wat = (ushort*)d_out + (size_t)M_ * C_;

    convert_x_kernel<<<2048, 256, 0, stream>>>(x, Xb, M_*C_/8);
    transpose_w_kernel<<<dim3(3*C_/64, C_/64), 256, 0, stream>>>(W_attn, Wat, C_, 3*C_);

    gemm8p_kernel<0><<<dim3(M_/128, 3*C_/256), 512, 0, stream>>>(
        Xb, Wat, b_attn, bQ, bK, Qb, Kb, Vt, nullptr, nullptr, C_, 3*C_);

    attn_kernel<<<2048, 256, 0, stream>>>(Qb, Kb, Vt, y);

    transpose_w_kernel<<<dim3(C_/64, C_/64), 256, 0, stream>>>(W_proj, Wpt, C_, C_);

    gemm8p_kernel<1><<<dim3(M_/128, C_/256), 512, 0, stream>>>(
        y, Wpt, nullptr, nullptr, nullptr, nullptr, nullptr, nullptr,
        out, b_proj, C_, C_);

    copy_bq_kernel<<<(NH_*D_ + 255)/256, 256, 0, stream>>>(
        bQ, out + (size_t)M_ * C_);
}

// Round 13
// 200.005 us; speedup vs baseline: 1.4081x; 1.0312x over previous
//
#include <hip/hip_runtime.h>
#include <hip/hip_bf16.h>

#define B_  4
#define T_  2048
#define C_  1024
#define NH_ 16
#define D_  64
#define BH_ (B_*NH_)   // 64
#define M_  (B_*T_)    // 8192

typedef __attribute__((ext_vector_type(8))) short short8;
typedef __attribute__((ext_vector_type(4))) short short4v;
typedef __attribute__((ext_vector_type(4))) float f32x4;

#define SC2 0.18033688011112043f   // (1/sqrt(64)) * log2(e)

__device__ __forceinline__ ushort f2bf(float f) {
    unsigned u = __float_as_uint(f);
    u += 0x7FFF + ((u >> 16) & 1);   // RNE
    return (ushort)(u >> 16);
}

__device__ __forceinline__ unsigned cvtpk(float lo, float hi) {
    unsigned r;
    asm("v_cvt_pk_bf16_f32 %0, %1, %2" : "=v"(r) : "v"(lo), "v"(hi));
    return r;
}

__device__ __forceinline__ void gload16(const void* g, void* lds) {
    __builtin_amdgcn_global_load_lds(
        (const __attribute__((address_space(1))) void*)g,
        (__attribute__((address_space(3))) void*)lds, 16, 0, 0);
}

// ---------------------------------------------------------------------------
// Fused prepass: [0,2048) convert x -> bf16; [2048,2816) transpose W_attn;
// [2816] copy bQ to output tuple slot.
// ---------------------------------------------------------------------------
__global__ __launch_bounds__(256) void prepass_kernel(
    const float* __restrict__ x, ushort* __restrict__ Xb,
    const float* __restrict__ Wa, ushort* __restrict__ Wat,
    const float* __restrict__ bQ, float* __restrict__ bqDst)
{
    __shared__ float t[64][65];
    const int bid = blockIdx.x;
    const int tid = threadIdx.x;

    if (bid < 2048) {
        const int n8 = M_*C_/8;
        const int stride = 2048 * 256;
        for (int idx = bid*256 + tid; idx < n8; idx += stride) {
            const float* p = x + (size_t)idx * 8;
            f32x4 a = *(const f32x4*)p;
            f32x4 b = *(const f32x4*)(p + 4);
            union { short8 v; ushort u[8]; } pk;
            #pragma unroll
            for (int j = 0; j < 4; ++j) { pk.u[j] = f2bf(a[j]); pk.u[4+j] = f2bf(b[j]); }
            *(short8*)&Xb[(size_t)idx * 8] = pk.v;
        }
    } else if (bid < 2816) {
        const int tb = bid - 2048;          // 0..767 = 48 x 16
        const int n0 = (tb % 48) * 64;
        const int k0 = (tb / 48) * 64;
        const int K = C_, N = 3*C_;
        #pragma unroll
        for (int it = 0; it < 16; ++it) {
            const int kr = it*4 + (tid >> 6);
            t[kr][tid & 63] = Wa[(size_t)(k0 + kr) * N + n0 + (tid & 63)];
        }
        __syncthreads();
        const int nr8 = tid >> 3;
        const int kc0 = (tid & 7) * 8;
        #pragma unroll
        for (int j = 0; j < 2; ++j) {
            const int nr = j*32 + nr8;
            union { short8 v; ushort u[8]; } pk;
            #pragma unroll
            for (int e = 0; e < 8; ++e) pk.u[e] = f2bf(t[kc0 + e][nr]);
            *(short8*)&Wat[(size_t)(n0 + nr) * K + k0 + kc0] = pk.v;
        }
    } else {
        for (int i = tid; i < NH_*D_; i += 256) bqDst[i] = bQ[i];
    }
}

// in [K][N] f32  ->  out [N][K] bf16   (used for W_proj after attn)
__global__ __launch_bounds__(256) void transpose_w_kernel(
    const float* __restrict__ in, ushort* __restrict__ out, int K, int N)
{
    __shared__ float t[64][65];
    const int tid = threadIdx.x;
    const int n0 = blockIdx.x * 64;
    const int k0 = blockIdx.y * 64;
    #pragma unroll
    for (int it = 0; it < 16; ++it) {
        const int kr = it*4 + (tid >> 6);
        t[kr][tid & 63] = in[(size_t)(k0 + kr) * N + n0 + (tid & 63)];
    }
    __syncthreads();
    const int nr8 = tid >> 3;
    const int kc0 = (tid & 7) * 8;
    #pragma unroll
    for (int j = 0; j < 2; ++j) {
        const int nr = j*32 + nr8;
        union { short8 v; ushort u[8]; } pk;
        #pragma unroll
        for (int e = 0; e < 8; ++e) pk.u[e] = f2bf(t[kc0 + e][nr]);
        *(short8*)&out[(size_t)(n0 + nr) * K + k0 + kc0] = pk.v;
    }
}

// ---------------------------------------------------------------------------
// 128x128-tile MFMA GEMM, BK=32, 4 waves each 64x64, global_load_lds
// width-16 staging, 3-buffer counted-vmcnt pipeline (r10 base).
// Flat 48KB LDS: As buf bi = SH + bi*4096, Bs buf bi = SH + 12288 + bi*4096;
// V epilogue reuses SH as TL[128][136] (34.8 KB <= 48 KB, in-bounds).
// 1-D grid, XCD M-stripe mapping (T1): MODE0 grid=1536 (64 m x 24 n),
// MODE1 grid=512 (64 m x 8 n); each XCD owns an 8-block M-stripe.
// MODE 0 V-section (n0>=2048): LDS-transpose -> coalesced 16B V^T stores.
// MODE 1: out fp32 + b_proj.
// ---------------------------------------------------------------------------
template<int MODE>
__global__ __launch_bounds__(256) void gemm128_kernel(
    const ushort* __restrict__ A, const ushort* __restrict__ Bt,
    const float* __restrict__ b_attn, const float* __restrict__ bQv,
    const float* __restrict__ bKv,
    ushort* __restrict__ Qb, ushort* __restrict__ Kb, ushort* __restrict__ Vt,
    float* __restrict__ outp, const float* __restrict__ b_proj,
    int K, int N)
{
    __shared__ ushort SH[24576];   // 48 KB flat: As 3x8KB | Bs 3x8KB

    const int tid  = threadIdx.x;
    const int lane = tid & 63;
    const int w    = tid >> 6;
    const int wr   = w >> 1, wc = w & 1;
    const int l16  = lane & 15, lg = lane >> 4;

    // XCD M-stripe mapping: bid -> (m-block, n-block)
    const int bid = blockIdx.x;
    const int xcd = bid & 7;
    const int idx = bid >> 3;
    const int m0  = (xcd*8 + (idx & 7)) * 128;
    const int n0  = (idx >> 3) * 128;

    const int srow = lane >> 2;          // 0..15
    const int scol = (lane & 3) * 8;     // k elems
    const ushort* aS = A  + (size_t)(m0 + w*32 + srow) * K + scol;
    const ushort* bS = Bt + (size_t)(n0 + w*32 + srow) * K + scol;

    f32x4 acc[4][4] = {};

    const int NT = K >> 5;

    #define STAGE(tk, bi)                                                     \
        do {                                                                  \
            const int kn_ = (tk) * 32;                                        \
            gload16(aS + kn_,                SH + (bi)*4096 + w*1024);        \
            gload16(aS + (size_t)16*K + kn_, SH + (bi)*4096 + w*1024 + 512);  \
            gload16(bS + kn_,                SH + 12288 + (bi)*4096 + w*1024);\
            gload16(bS + (size_t)16*K + kn_, SH + 12288 + (bi)*4096 + w*1024 + 512);\
        } while (0)

    STAGE(0, 0);
    STAGE(1, 1);
    asm volatile("s_waitcnt vmcnt(4)" ::: "memory");
    __builtin_amdgcn_s_barrier();

    for (int t = 0; t < NT; ++t) {
        const int cur = t % 3;
        if (t + 2 < NT)
            STAGE(t + 2, (t + 2) % 3);

        short8 af[4], bf[4];
        #pragma unroll
        for (int i = 0; i < 4; ++i) {
            af[i] = *(const short8*)&SH[cur*4096 + (wr*64 + i*16 + l16)*32 + lg*8];
            bf[i] = *(const short8*)&SH[12288 + cur*4096 + (wc*64 + i*16 + l16)*32 + lg*8];
        }
        #pragma unroll
        for (int mi = 0; mi < 4; ++mi)
            #pragma unroll
            for (int ni = 0; ni < 4; ++ni)
                acc[mi][ni] = __builtin_amdgcn_mfma_f32_16x16x32_bf16(
                    af[mi], bf[ni], acc[mi][ni], 0, 0, 0);

        if (t + 1 < NT) {
            if (t + 2 < NT)
                asm volatile("s_waitcnt vmcnt(4)" ::: "memory");
            else
                asm volatile("s_waitcnt vmcnt(0)" ::: "memory");
            __builtin_amdgcn_s_barrier();
        }
    }
    #undef STAGE

    if constexpr (MODE == 0) {
        if (n0 >= 2048) {
            // ---- V block: LDS transpose -> coalesced V^T stores ----
            __syncthreads();
            ushort* TL = SH;   // [128 n][136] bf16 = 34.8 KB (fits 48 KB)
            #pragma unroll
            for (int ni = 0; ni < 4; ++ni) {
                const int nl = wc*64 + ni*16 + l16;      // 0..127
                const float ba = b_attn[n0 + nl];
                #pragma unroll
                for (int mi = 0; mi < 4; ++mi)
                    #pragma unroll
                    for (int r = 0; r < 4; ++r) {
                        const int ml = wr*64 + mi*16 + lg*4 + r;
                        TL[nl*136 + ml] = f2bf(acc[mi][ni][r] + ba);
                    }
            }
            __syncthreads();
            const int bblk = m0 >> 11;
            const int tblk = m0 & 2047;
            const int h0   = (n0 & 1023) >> 6;
            #pragma unroll
            for (int it = 0; it < 8; ++it) {
                const int row = w*32 + it*4 + (lane >> 4);   // 0..127
                const int d   = row & 63;
                const int h   = h0 + (row >> 6);
                const short8 v = *(const short8*)&TL[row*136 + (lane & 15)*8];
                *(short8*)(Vt + ((size_t)(bblk*NH_ + h)*D_ + d)*T_ + tblk + (lane & 15)*8) = v;
            }
        } else {
            // ---- Q / K block: scatter (32B-contiguous per 16 lanes) ----
            #pragma unroll
            for (int ni = 0; ni < 4; ++ni) {
                const int n = n0 + wc*64 + ni*16 + l16;
                const int sec = n >> 10;      // 0=Q 1=K
                const int nn  = n & 1023;
                const int h = nn >> 6, d = nn & 63;
                const float ba = b_attn[n];
                #pragma unroll
                for (int mi = 0; mi < 4; ++mi) {
                    #pragma unroll
                    for (int r = 0; r < 4; ++r) {
                        const int m = m0 + wr*64 + mi*16 + lg*4 + r;
                        const int b = m >> 11, t = m & 2047;
                        float v = acc[mi][ni][r] + ba;
                        if (sec == 0) {
                            v = (v + bQv[nn]) * SC2;
                            Qb[((size_t)(b*NH_ + h)*T_ + t)*D_ + d] = f2bf(v);
                        } else {
                            v += bKv[nn];
                            Kb[((size_t)(b*NH_ + h)*T_ + t)*D_ + d] = f2bf(v);
                        }
                    }
                }
            }
        }
    } else {
        #pragma unroll
        for (int ni = 0; ni < 4; ++ni) {
            const int n = n0 + wc*64 + ni*16 + l16;
            const float bp = b_proj[n];
            #pragma unroll
            for (int mi = 0; mi < 4; ++mi)
                #pragma unroll
                for (int r = 0; r < 4; ++r) {
                    const int m = m0 + wr*64 + mi*16 + lg*4 + r;
                    outp[(size_t)m * N + n] = acc[mi][ni][r] + bp;
                }
        }
    }
}

// ---------------------------------------------------------------------------
// Flash attention v7 (unchanged): online softmax + defer-rescale, 64-q
// supertile per block, grid 2048, heavy-first + XCD-chunked, K/V
// double-buffered in LDS via global_load_lds, XOR-swizzled reads.
// ---------------------------------------------------------------------------
__global__ __launch_bounds__(256, 5) void attn_kernel(
    const ushort* __restrict__ Qb, const ushort* __restrict__ Kb,
    const ushort* __restrict__ Vt, ushort* __restrict__ y)
{
    __shared__ char lds[2][16384];   // [buf][ K 8KB | V 8KB ]

    const int tid  = threadIdx.x;
    const int lane = tid & 63;
    const int w    = tid >> 6;
    const int l16  = lane & 15, lg = lane >> 4;
    const int bid  = blockIdx.x;
    const int xcd  = bid & 7;
    const int idx  = bid >> 3;                 // 0..255
    const int bh   = (xcd << 3) | (idx & 7);   // 8 bh per XCD
    const int p    = 31 - (idx >> 3);          // heavy supertiles first
    const int b    = bh >> 4, h = bh & 15;
    const size_t kvb = (size_t)bh * T_ * D_;
    const size_t vtb = (size_t)bh * D_ * T_;

    int srow[2], scol[2];
    #pragma unroll
    for (int i = 0; i < 2; ++i) {
        const int l = w*2048 + i*1024 + lane*16;
        const int r = l >> 7;
        const int c = (l & 127) ^ ((r & 7) << 4);
        srow[i] = r; scol[i] = c >> 1;
    }

    const f32x4 z4 = {0.f, 0.f, 0.f, 0.f};

    const int qw = p * 64 + w * 16;

    short8 qf[2];
    #pragma unroll
    for (int c = 0; c < 2; ++c)
        qf[c] = *(const short8*)(Qb + kvb +
                    (size_t)(qw + l16)*D_ + c*32 + lg*8);

    f32x4 o[4] = {};
    float mrow = -1e30f;
    float lrow = 0.f;
    const int nt = p + 1;

    #pragma unroll
    for (int i = 0; i < 2; ++i) {
        gload16(Kb + kvb + (size_t)srow[i]*D_ + scol[i],
                &lds[0][w*2048 + i*1024]);
        gload16(Vt + vtb + (size_t)srow[i]*T_ + scol[i],
                &lds[0][8192 + w*2048 + i*1024]);
    }

    #pragma unroll 1
    for (int t = 0; t < nt; ++t) {
        const int kb = t * 64;
        if (t + 1 < nt) {
            char* Lb = lds[(t + 1) & 1];
            const int kb1 = kb + 64;
            #pragma unroll
            for (int i = 0; i < 2; ++i) {
                gload16(Kb + kvb + (size_t)(kb1 + srow[i])*D_ + scol[i],
                        Lb + w*2048 + i*1024);
                gload16(Vt + vtb + (size_t)srow[i]*T_ + kb1 + scol[i],
                        Lb + 8192 + w*2048 + i*1024);
            }
            asm volatile("s_waitcnt vmcnt(4)" ::: "memory");
        } else {
            asm volatile("s_waitcnt vmcnt(0)" ::: "memory");
        }
        __builtin_amdgcn_s_barrier();

        {
            const char* Lk = lds[t & 1];
            const char* Lv = lds[t & 1] + 8192;

            f32x4 s[4];
            #pragma unroll
            for (int t4 = 0; t4 < 4; ++t4) {
                const int r = t4*16 + l16;
                const int m = (r & 7) << 4;
                const short8 kc0 = *(const short8*)(Lk + r*128 + (( lg*16     ) ^ m));
                const short8 kc1 = *(const short8*)(Lk + r*128 + ((64 + lg*16 ) ^ m));
                s[t4] = __builtin_amdgcn_mfma_f32_16x16x32_bf16(kc0, qf[0], z4,    0, 0, 0);
                s[t4] = __builtin_amdgcn_mfma_f32_16x16x32_bf16(kc1, qf[1], s[t4], 0, 0, 0);
            }

            const bool full = (kb + 63 <= qw);
            float x[4][4];
            #pragma unroll
            for (int t4 = 0; t4 < 4; ++t4)
                #pragma unroll
                for (int r = 0; r < 4; ++r) {
                    float v = s[t4][r];
                    if (!full)
                        v = (kb + t4*16 + lg*4 + r <= qw + l16) ? v : -1e30f;
                    x[t4][r] = v;
                }
            float vm0 = fmaxf(fmaxf(x[0][0], x[0][1]), fmaxf(x[0][2], x[0][3]));
            float vm1 = fmaxf(fmaxf(x[1][0], x[1][1]), fmaxf(x[1][2], x[1][3]));
            float vm2 = fmaxf(fmaxf(x[2][0], x[2][1]), fmaxf(x[2][2], x[2][3]));
            float vm3 = fmaxf(fmaxf(x[3][0], x[3][1]), fmaxf(x[3][2], x[3][3]));
            float vm  = fmaxf(fmaxf(vm0, vm1), fmaxf(vm2, vm3));
            vm = fmaxf(vm, __shfl_xor(vm, 16, 64));
            vm = fmaxf(vm, __shfl_xor(vm, 32, 64));
            const float mn = fmaxf(mrow, vm);
            float rs = 0.f;
            #pragma unroll
            for (int t4 = 0; t4 < 4; ++t4)
                #pragma unroll
                for (int r = 0; r < 4; ++r) {
                    const float pe = __builtin_amdgcn_exp2f(x[t4][r] - mn);
                    x[t4][r] = pe;
                    rs += pe;
                }
            rs += __shfl_xor(rs, 16, 64);
            rs += __shfl_xor(rs, 32, 64);
            if (__all(vm <= mrow)) {
                lrow += rs;
            } else {
                const float al = __builtin_amdgcn_exp2f(mrow - mn);
                lrow = lrow*al + rs;
                #pragma unroll
                for (int cb = 0; cb < 4; ++cb)
                    #pragma unroll
                    for (int r = 0; r < 4; ++r)
                        o[cb][r] *= al;
            }
            mrow = mn;

            union { unsigned u[4]; short8 v; } p0, p1;
            p0.u[0] = cvtpk(x[0][0], x[0][1]);
            p0.u[1] = cvtpk(x[0][2], x[0][3]);
            p0.u[2] = cvtpk(x[1][0], x[1][1]);
            p0.u[3] = cvtpk(x[1][2], x[1][3]);
            p1.u[0] = cvtpk(x[2][0], x[2][1]);
            p1.u[1] = cvtpk(x[2][2], x[2][3]);
            p1.u[2] = cvtpk(x[3][0], x[3][1]);
            p1.u[3] = cvtpk(x[3][2], x[3][3]);

            #pragma unroll
            for (int cb = 0; cb < 4; ++cb) {
                const int d = cb*16 + l16;
                const int mv = (d & 7) << 4;
                const char* vb = Lv + d*128;
                union { short8 v; short4v hh[2]; } v0, v1;
                v0.hh[0] = *(const short4v*)(vb + ((lg*8     ) ^ mv));
                v0.hh[1] = *(const short4v*)(vb + ((lg*8 + 32) ^ mv));
                v1.hh[0] = *(const short4v*)(vb + ((lg*8 + 64) ^ mv));
                v1.hh[1] = *(const short4v*)(vb + ((lg*8 + 96) ^ mv));
                o[cb] = __builtin_amdgcn_mfma_f32_16x16x32_bf16(v0.v, p0.v, o[cb], 0, 0, 0);
                o[cb] = __builtin_amdgcn_mfma_f32_16x16x32_bf16(v1.v, p1.v, o[cb], 0, 0, 0);
            }
        }
        __builtin_amdgcn_s_barrier();
    }

    {
        const float inv = 1.0f / lrow;
        const int q = qw + l16;
        ushort* yr = y + ((size_t)b*T_ + q)*C_ + h*D_ + lg*4;
        #pragma unroll
        for (int cb = 0; cb < 4; ++cb) {
            union { unsigned u[2]; short4v v; } st;
            st.u[0] = cvtpk(o[cb][0]*inv, o[cb][1]*inv);
            st.u[1] = cvtpk(o[cb][2]*inv, o[cb][3]*inv);
            *(short4v*)(yr + cb*16) = st.v;
        }
    }
}

extern "C" void kernel_launch(void* const* d_in, const int* in_sizes, int n_in,
                              void* d_out, int out_size, void* d_ws, size_t ws_size,
                              hipStream_t stream)
{
    const float* x      = (const float*)d_in[0];
    const float* W_attn = (const float*)d_in[1];
    const float* b_attn = (const float*)d_in[2];
    const float* W_proj = (const float*)d_in[3];
    const float* b_proj = (const float*)d_in[4];
    const float* bQ     = (const float*)d_in[5];
    const float* bK     = (const float*)d_in[6];
    float* out = (float*)d_out;

    const size_t HE = (size_t)BH_ * T_ * D_;   // 8M elems
    ushort* Qb = (ushort*)d_ws;
    ushort* Kb = Qb + HE;
    ushort* Vt = Kb + HE;
    ushort* y  = Vt + HE;
    ushort* Wpt = (ushort*)d_ws;               // aliases Qb (dead after attn)

    ushort* Xb  = (ushort*)d_out;              // scratch in d_out (dead before GEMM2)
    ushort* Wat = (ushort*)d_out + (size_t)M_ * C_;

    // 1) fused prepass: x->bf16, W_attn^T, bQ tuple copy
    prepass_kernel<<<2817, 256, 0, stream>>>(x, Xb, W_attn, Wat,
                                             bQ, out + (size_t)M_ * C_);

    // 2) QKV GEMM (64 m-blocks x 24 n-blocks, XCD-striped)
    gemm128_kernel<0><<<1536, 256, 0, stream>>>(
        Xb, Wat, b_attn, bQ, bK, Qb, Kb, Vt, nullptr, nullptr, C_, 3*C_);

    // 3) causal flash attention
    attn_kernel<<<2048, 256, 0, stream>>>(Qb, Kb, Vt, y);

    // 4) W_proj^T into dead Qb region
    transpose_w_kernel<<<dim3(C_/64, C_/64), 256, 0, stream>>>(W_proj, Wpt, C_, C_);

    // 5) out = y @ W_proj + b_proj (64 x 8, XCD-striped)
    gemm128_kernel<1><<<512, 256, 0, stream>>>(
        y, Wpt, nullptr, nullptr, nullptr, nullptr, nullptr, nullptr,
        out, b_proj, C_, C_);
}

// Round 14
// 197.118 us; speedup vs baseline: 1.4287x; 1.0146x over previous
//
#include <hip/hip_runtime.h>
#include <hip/hip_bf16.h>

#define B_  4
#define T_  2048
#define C_  1024
#define NH_ 16
#define D_  64
#define BH_ (B_*NH_)   // 64
#define M_  (B_*T_)    // 8192

typedef __attribute__((ext_vector_type(8))) short short8;
typedef __attribute__((ext_vector_type(4))) short short4v;
typedef __attribute__((ext_vector_type(4))) float f32x4;

#define SC2 0.18033688011112043f   // (1/sqrt(64)) * log2(e)

__device__ __forceinline__ ushort f2bf(float f) {
    unsigned u = __float_as_uint(f);
    u += 0x7FFF + ((u >> 16) & 1);   // RNE
    return (ushort)(u >> 16);
}

__device__ __forceinline__ unsigned cvtpk(float lo, float hi) {
    unsigned r;
    asm("v_cvt_pk_bf16_f32 %0, %1, %2" : "=v"(r) : "v"(lo), "v"(hi));
    return r;
}

__device__ __forceinline__ void gload16(const void* g, void* lds) {
    __builtin_amdgcn_global_load_lds(
        (const __attribute__((address_space(1))) void*)g,
        (__attribute__((address_space(3))) void*)lds, 16, 0, 0);
}

// ---------------------------------------------------------------------------
// Fused prepass: [0,2048) convert x -> bf16; [2048,2816) transpose W_attn;
// [2816] copy bQ to output tuple slot.
// ---------------------------------------------------------------------------
__global__ __launch_bounds__(256) void prepass_kernel(
    const float* __restrict__ x, ushort* __restrict__ Xb,
    const float* __restrict__ Wa, ushort* __restrict__ Wat,
    const float* __restrict__ bQ, float* __restrict__ bqDst)
{
    __shared__ float t[64][65];
    const int bid = blockIdx.x;
    const int tid = threadIdx.x;

    if (bid < 2048) {
        const int n8 = M_*C_/8;
        const int stride = 2048 * 256;
        for (int idx = bid*256 + tid; idx < n8; idx += stride) {
            const float* p = x + (size_t)idx * 8;
            f32x4 a = *(const f32x4*)p;
            f32x4 b = *(const f32x4*)(p + 4);
            union { short8 v; ushort u[8]; } pk;
            #pragma unroll
            for (int j = 0; j < 4; ++j) { pk.u[j] = f2bf(a[j]); pk.u[4+j] = f2bf(b[j]); }
            *(short8*)&Xb[(size_t)idx * 8] = pk.v;
        }
    } else if (bid < 2816) {
        const int tb = bid - 2048;          // 0..767 = 48 x 16
        const int n0 = (tb % 48) * 64;
        const int k0 = (tb / 48) * 64;
        const int K = C_, N = 3*C_;
        #pragma unroll
        for (int it = 0; it < 16; ++it) {
            const int kr = it*4 + (tid >> 6);
            t[kr][tid & 63] = Wa[(size_t)(k0 + kr) * N + n0 + (tid & 63)];
        }
        __syncthreads();
        const int nr8 = tid >> 3;
        const int kc0 = (tid & 7) * 8;
        #pragma unroll
        for (int j = 0; j < 2; ++j) {
            const int nr = j*32 + nr8;
            union { short8 v; ushort u[8]; } pk;
            #pragma unroll
            for (int e = 0; e < 8; ++e) pk.u[e] = f2bf(t[kc0 + e][nr]);
            *(short8*)&Wat[(size_t)(n0 + nr) * K + k0 + kc0] = pk.v;
        }
    } else {
        for (int i = tid; i < NH_*D_; i += 256) bqDst[i] = bQ[i];
    }
}

// in [K][N] f32  ->  out [N][K] bf16   (used for W_proj after attn)
__global__ __launch_bounds__(256) void transpose_w_kernel(
    const float* __restrict__ in, ushort* __restrict__ out, int K, int N)
{
    __shared__ float t[64][65];
    const int tid = threadIdx.x;
    const int n0 = blockIdx.x * 64;
    const int k0 = blockIdx.y * 64;
    #pragma unroll
    for (int it = 0; it < 16; ++it) {
        const int kr = it*4 + (tid >> 6);
        t[kr][tid & 63] = in[(size_t)(k0 + kr) * N + n0 + (tid & 63)];
    }
    __syncthreads();
    const int nr8 = tid >> 3;
    const int kc0 = (tid & 7) * 8;
    #pragma unroll
    for (int j = 0; j < 2; ++j) {
        const int nr = j*32 + nr8;
        union { short8 v; ushort u[8]; } pk;
        #pragma unroll
        for (int e = 0; e < 8; ++e) pk.u[e] = f2bf(t[kc0 + e][nr]);
        *(short8*)&out[(size_t)(n0 + nr) * K + k0 + kc0] = pk.v;
    }
}

// ---------------------------------------------------------------------------
// GEMM1 (QKV): m201-geometry 8-phase kernel.
// Tile 256x256, 8 waves (2M x 4N), per-wave output 128x64 (acc 8x4),
// BK=64 in two k-halves of 32. LDS = 2 tile-buffers x (A 32KB + B 32KB)
// = 128 KB. Per tile: 4 phases; phase p stages half-tile H(t+1,p) where
// H order = {A-k0, B-k0, A-k1, B-k1} (16 KB each, 2 gload16/wave).
// Counted vmcnt(4) at the kh boundaries (end of p1 / p3): per-wave
// outstanding is 8 loads, oldest 4 = exactly the 2 halves needed next.
// vmcnt(0) only at the last tile. Swizzle: 16B k-slot ^= (row>>1)&3,
// inverse applied to the per-lane GLOBAL source (LDS dest linear).
// Epilogue: Q (pre-scaled), K scatter; V via LDS transpose (2 m-passes)
// -> 256B-contiguous V^T stores.
// ---------------------------------------------------------------------------
__global__ __launch_bounds__(512, 2) void gemmqkv_kernel(
    const ushort* __restrict__ A, const ushort* __restrict__ Bt,
    const float* __restrict__ b_attn, const float* __restrict__ bQv,
    const float* __restrict__ bKv,
    ushort* __restrict__ Qb, ushort* __restrict__ Kb, ushort* __restrict__ Vt)
{
    __shared__ ushort SH[65536];   // 128 KB

    const int K = C_;              // 1024
    const int NT = 16;             // K / 64
    const int tid  = threadIdx.x;
    const int lane = tid & 63;
    const int w    = tid >> 6;     // 0..7
    const int wr   = w >> 2;       // 0..1 (M half)
    const int wc   = w & 3;        // 0..3 (N quarter)
    const int l16  = lane & 15, lg = lane >> 4;

    // XCD-chunked grid: 384 blocks = 8 XCD x (4 m x 12 n)
    const int bid = blockIdx.x;
    const int xcd = bid & 7;
    const int idx = bid >> 3;                  // 0..47
    const int m0  = (xcd*4 + (idx & 3)) * 256;
    const int n0  = (idx >> 2) * 256;

    // staging: per gload16, lane -> row base+(lane>>2), 16B slot lane&3,
    // source k-slot = slot ^ ((row>>1)&3)  (rows per call: 16)
    const int gsw = 8 * ((lane & 3) ^ ((lane >> 3) & 3));
    const ushort* aBase = A  + (size_t)(m0 + w*32 + (lane >> 2)) * K + gsw;
    const ushort* bBase = Bt + (size_t)(n0 + w*32 + (lane >> 2)) * K + gsw;
    // frag read k-slot offset (ushorts): (lg ^ ((row>>1)&3))*8, row≡l16 mod 16
    const int fsw = ((lg ^ ((l16 >> 1) & 3)) << 3);

    f32x4 acc[8][4] = {};

    // LDS map (ushort offsets): A half(kh) of buf b: b*16384 + kh*8192
    //                           B half(kh):  32768 + b*16384 + kh*8192
    #define STG_A(tk, kh)                                                     \
        do { ushort* d_ = SH + ((tk)&1)*16384 + (kh)*8192 + w*1024;           \
             const ushort* s_ = aBase + (tk)*64 + (kh)*32;                    \
             gload16(s_, d_); gload16(s_ + 16*K, d_ + 512); } while (0)
    #define STG_B(tk, kh)                                                     \
        do { ushort* d_ = SH + 32768 + ((tk)&1)*16384 + (kh)*8192 + w*1024;   \
             const ushort* s_ = bBase + (tk)*64 + (kh)*32;                    \
             gload16(s_, d_); gload16(s_ + 16*K, d_ + 512); } while (0)
    #define BAR()   __builtin_amdgcn_s_barrier()
    #define LGKM()  do { asm volatile("s_waitcnt lgkmcnt(0)" ::: "memory");   \
                         __builtin_amdgcn_sched_barrier(0); } while (0)
    #define VMC4()  asm volatile("s_waitcnt vmcnt(4)" ::: "memory")
    #define VMC0()  asm volatile("s_waitcnt vmcnt(0)" ::: "memory")

    // prologue: stage tile 0 (4 halves = 8 loads/wave); oldest 4 = A-k0,B-k0
    STG_A(0, 0); STG_B(0, 0); STG_A(0, 1); STG_B(0, 1);
    VMC4();
    BAR();

    #pragma unroll 1
    for (int t = 0; t < NT; ++t) {
        const int cb = (t & 1) * 16384;
        const bool st = (t + 1 < NT);
        short8 bf[4], af[4];

        // ---- phase 0: rows 0..3, kh 0 ----
        {
            const ushort* Ah = SH + cb;
            const ushort* Bh = SH + 32768 + cb;
            #pragma unroll
            for (int ni = 0; ni < 4; ++ni)
                bf[ni] = *(const short8*)&Bh[(wc*64 + ni*16 + l16)*32 + fsw];
            #pragma unroll
            for (int q = 0; q < 4; ++q)
                af[q] = *(const short8*)&Ah[(wr*128 + q*16 + l16)*32 + fsw];
            if (st) STG_A(t + 1, 0);
            BAR(); LGKM();
            __builtin_amdgcn_s_setprio(1);
            #pragma unroll
            for (int q = 0; q < 4; ++q)
                #pragma unroll
                for (int ni = 0; ni < 4; ++ni)
                    acc[q][ni] = __builtin_amdgcn_mfma_f32_16x16x32_bf16(
                        af[q], bf[ni], acc[q][ni], 0, 0, 0);
            __builtin_amdgcn_s_setprio(0);
            BAR();
        }
        // ---- phase 1: rows 4..7, kh 0 ----
        {
            const ushort* Ah = SH + cb;
            #pragma unroll
            for (int q = 0; q < 4; ++q)
                af[q] = *(const short8*)&Ah[(wr*128 + (4+q)*16 + l16)*32 + fsw];
            if (st) STG_B(t + 1, 0);
            BAR(); LGKM();
            __builtin_amdgcn_s_setprio(1);
            #pragma unroll
            for (int q = 0; q < 4; ++q)
                #pragma unroll
                for (int ni = 0; ni < 4; ++ni)
                    acc[4+q][ni] = __builtin_amdgcn_mfma_f32_16x16x32_bf16(
                        af[q], bf[ni], acc[4+q][ni], 0, 0, 0);
            __builtin_amdgcn_s_setprio(0);
            if (st) VMC4(); else VMC0();   // release A-k1,B-k1 of tile t
            BAR();
        }
        // ---- phase 2: rows 0..3, kh 1 ----
        {
            const ushort* Ah = SH + cb + 8192;
            const ushort* Bh = SH + 32768 + cb + 8192;
            #pragma unroll
            for (int ni = 0; ni < 4; ++ni)
                bf[ni] = *(const short8*)&Bh[(wc*64 + ni*16 + l16)*32 + fsw];
            #pragma unroll
            for (int q = 0; q < 4; ++q)
                af[q] = *(const short8*)&Ah[(wr*128 + q*16 + l16)*32 + fsw];
            if (st) STG_A(t + 1, 1);
            BAR(); LGKM();
            __builtin_amdgcn_s_setprio(1);
            #pragma unroll
            for (int q = 0; q < 4; ++q)
                #pragma unroll
                for (int ni = 0; ni < 4; ++ni)
                    acc[q][ni] = __builtin_amdgcn_mfma_f32_16x16x32_bf16(
                        af[q], bf[ni], acc[q][ni], 0, 0, 0);
            __builtin_amdgcn_s_setprio(0);
            BAR();
        }
        // ---- phase 3: rows 4..7, kh 1 ----
        {
            const ushort* Ah = SH + cb + 8192;
            #pragma unroll
            for (int q = 0; q < 4; ++q)
                af[q] = *(const short8*)&Ah[(wr*128 + (4+q)*16 + l16)*32 + fsw];
            if (st) STG_B(t + 1, 1);
            BAR(); LGKM();
            __builtin_amdgcn_s_setprio(1);
            #pragma unroll
            for (int q = 0; q < 4; ++q)
                #pragma unroll
                for (int ni = 0; ni < 4; ++ni)
                    acc[4+q][ni] = __builtin_amdgcn_mfma_f32_16x16x32_bf16(
                        af[q], bf[ni], acc[4+q][ni], 0, 0, 0);
            __builtin_amdgcn_s_setprio(0);
            if (st) VMC4();                 // release A-k0,B-k0 of tile t+1
            BAR();
        }
    }
    #undef STG_A
    #undef STG_B

    // ---------------- epilogue ----------------
    if (n0 < 2048) {
        // Q / K scatter (32B-contiguous per 16 lanes)
        #pragma unroll
        for (int ni = 0; ni < 4; ++ni) {
            const int n = n0 + wc*64 + ni*16 + l16;
            const int sec = n >> 10;      // 0=Q 1=K
            const int nn  = n & 1023;
            const int h = nn >> 6, d = nn & 63;
            const float ba = b_attn[n];
            #pragma unroll
            for (int mi = 0; mi < 8; ++mi) {
                #pragma unroll
                for (int r = 0; r < 4; ++r) {
                    const int m = m0 + wr*128 + mi*16 + lg*4 + r;
                    const int b = m >> 11, tt = m & 2047;
                    float v = acc[mi][ni][r] + ba;
                    if (sec == 0) {
                        v = (v + bQv[nn]) * SC2;
                        Qb[((size_t)(b*NH_ + h)*T_ + tt)*D_ + d] = f2bf(v);
                    } else {
                        v += bKv[nn];
                        Kb[((size_t)(b*NH_ + h)*T_ + tt)*D_ + d] = f2bf(v);
                    }
                }
            }
        }
    } else {
        // V block: LDS transpose in two m-passes -> coalesced V^T stores
        ushort* TL = SH;                   // [256 n][132] bf16 = 67.6 KB
        const int bblk = m0 >> 11;
        const int tcol0 = m0 & 2047;
        const int h0 = (n0 & 1023) >> 6;
        #pragma unroll 1
        for (int mh = 0; mh < 2; ++mh) {
            __syncthreads();
            if (wr == mh) {
                #pragma unroll
                for (int ni = 0; ni < 4; ++ni) {
                    const int nl = wc*64 + ni*16 + l16;
                    const float ba = b_attn[n0 + nl];
                    #pragma unroll
                    for (int mi = 0; mi < 8; ++mi)
                        #pragma unroll
                        for (int r = 0; r < 4; ++r)
                            TL[nl*132 + mi*16 + lg*4 + r] =
                                f2bf(acc[mi][ni][r] + ba);
                }
            }
            __syncthreads();
            #pragma unroll
            for (int it = 0; it < 8; ++it) {
                const int row = w*32 + it*4 + lg;     // 0..255 (n-local)
                const int d = row & 63;
                const int h = h0 + (row >> 6);
                const short8 v = *(const short8*)&TL[row*132 + l16*8];
                *(short8*)(Vt + ((size_t)(bblk*NH_ + h)*D_ + d)*T_
                           + tcol0 + mh*128 + l16*8) = v;
            }
        }
    }
}

// ---------------------------------------------------------------------------
// GEMM2: r13 128x128 3-buffer counted-vmcnt kernel (MODE1 path), XCD-striped.
// ---------------------------------------------------------------------------
__global__ __launch_bounds__(256) void gemm2_kernel(
    const ushort* __restrict__ A, const ushort* __restrict__ Bt,
    float* __restrict__ outp, const float* __restrict__ b_proj,
    int K, int N)
{
    __shared__ ushort SH[24576];   // 48 KB flat: As 3x8KB | Bs 3x8KB

    const int tid  = threadIdx.x;
    const int lane = tid & 63;
    const int w    = tid >> 6;
    const int wr   = w >> 1, wc = w & 1;
    const int l16  = lane & 15, lg = lane >> 4;

    const int bid = blockIdx.x;
    const int xcd = bid & 7;
    const int idx = bid >> 3;
    const int m0  = (xcd*8 + (idx & 7)) * 128;
    const int n0  = (idx >> 3) * 128;

    const int srow = lane >> 2;
    const int scol = (lane & 3) * 8;
    const ushort* aS = A  + (size_t)(m0 + w*32 + srow) * K + scol;
    const ushort* bS = Bt + (size_t)(n0 + w*32 + srow) * K + scol;

    f32x4 acc[4][4] = {};
    const int NT = K >> 5;

    #define STAGE(tk, bi)                                                     \
        do {                                                                  \
            const int kn_ = (tk) * 32;                                        \
            gload16(aS + kn_,                SH + (bi)*4096 + w*1024);        \
            gload16(aS + (size_t)16*K + kn_, SH + (bi)*4096 + w*1024 + 512);  \
            gload16(bS + kn_,                SH + 12288 + (bi)*4096 + w*1024);\
            gload16(bS + (size_t)16*K + kn_, SH + 12288 + (bi)*4096 + w*1024 + 512);\
        } while (0)

    STAGE(0, 0);
    STAGE(1, 1);
    asm volatile("s_waitcnt vmcnt(4)" ::: "memory");
    __builtin_amdgcn_s_barrier();

    for (int t = 0; t < NT; ++t) {
        const int cur = t % 3;
        if (t + 2 < NT)
            STAGE(t + 2, (t + 2) % 3);

        short8 af[4], bf[4];
        #pragma unroll
        for (int i = 0; i < 4; ++i) {
            af[i] = *(const short8*)&SH[cur*4096 + (wr*64 + i*16 + l16)*32 + lg*8];
            bf[i] = *(const short8*)&SH[12288 + cur*4096 + (wc*64 + i*16 + l16)*32 + lg*8];
        }
        #pragma unroll
        for (int mi = 0; mi < 4; ++mi)
            #pragma unroll
            for (int ni = 0; ni < 4; ++ni)
                acc[mi][ni] = __builtin_amdgcn_mfma_f32_16x16x32_bf16(
                    af[mi], bf[ni], acc[mi][ni], 0, 0, 0);

        if (t + 1 < NT) {
            if (t + 2 < NT)
                asm volatile("s_waitcnt vmcnt(4)" ::: "memory");
            else
                asm volatile("s_waitcnt vmcnt(0)" ::: "memory");
            __builtin_amdgcn_s_barrier();
        }
    }
    #undef STAGE

    #pragma unroll
    for (int ni = 0; ni < 4; ++ni) {
        const int n = n0 + wc*64 + ni*16 + l16;
        const float bp = b_proj[n];
        #pragma unroll
        for (int mi = 0; mi < 4; ++mi)
            #pragma unroll
            for (int r = 0; r < 4; ++r) {
                const int m = m0 + wr*64 + mi*16 + lg*4 + r;
                outp[(size_t)m * N + n] = acc[mi][ni][r] + bp;
            }
    }
}

// ---------------------------------------------------------------------------
// Flash attention v7 (unchanged from r13).
// ---------------------------------------------------------------------------
__global__ __launch_bounds__(256, 5) void attn_kernel(
    const ushort* __restrict__ Qb, const ushort* __restrict__ Kb,
    const ushort* __restrict__ Vt, ushort* __restrict__ y)
{
    __shared__ char lds[2][16384];   // [buf][ K 8KB | V 8KB ]

    const int tid  = threadIdx.x;
    const int lane = tid & 63;
    const int w    = tid >> 6;
    const int l16  = lane & 15, lg = lane >> 4;
    const int bid  = blockIdx.x;
    const int xcd  = bid & 7;
    const int idx  = bid >> 3;                 // 0..255
    const int bh   = (xcd << 3) | (idx & 7);   // 8 bh per XCD
    const int p    = 31 - (idx >> 3);          // heavy supertiles first
    const int b    = bh >> 4, h = bh & 15;
    const size_t kvb = (size_t)bh * T_ * D_;
    const size_t vtb = (size_t)bh * D_ * T_;

    int srow[2], scol[2];
    #pragma unroll
    for (int i = 0; i < 2; ++i) {
        const int l = w*2048 + i*1024 + lane*16;
        const int r = l >> 7;
        const int c = (l & 127) ^ ((r & 7) << 4);
        srow[i] = r; scol[i] = c >> 1;
    }

    const f32x4 z4 = {0.f, 0.f, 0.f, 0.f};

    const int qw = p * 64 + w * 16;

    short8 qf[2];
    #pragma unroll
    for (int c = 0; c < 2; ++c)
        qf[c] = *(const short8*)(Qb + kvb +
                    (size_t)(qw + l16)*D_ + c*32 + lg*8);

    f32x4 o[4] = {};
    float mrow = -1e30f;
    float lrow = 0.f;
    const int nt = p + 1;

    #pragma unroll
    for (int i = 0; i < 2; ++i) {
        gload16(Kb + kvb + (size_t)srow[i]*D_ + scol[i],
                &lds[0][w*2048 + i*1024]);
        gload16(Vt + vtb + (size_t)srow[i]*T_ + scol[i],
                &lds[0][8192 + w*2048 + i*1024]);
    }

    #pragma unroll 1
    for (int t = 0; t < nt; ++t) {
        const int kb = t * 64;
        if (t + 1 < nt) {
            char* Lb = lds[(t + 1) & 1];
            const int kb1 = kb + 64;
            #pragma unroll
            for (int i = 0; i < 2; ++i) {
                gload16(Kb + kvb + (size_t)(kb1 + srow[i])*D_ + scol[i],
                        Lb + w*2048 + i*1024);
                gload16(Vt + vtb + (size_t)srow[i]*T_ + kb1 + scol[i],
                        Lb + 8192 + w*2048 + i*1024);
            }
            asm volatile("s_waitcnt vmcnt(4)" ::: "memory");
        } else {
            asm volatile("s_waitcnt vmcnt(0)" ::: "memory");
        }
        __builtin_amdgcn_s_barrier();

        {
            const char* Lk = lds[t & 1];
            const char* Lv = lds[t & 1] + 8192;

            f32x4 s[4];
            #pragma unroll
            for (int t4 = 0; t4 < 4; ++t4) {
                const int r = t4*16 + l16;
                const int m = (r & 7) << 4;
                const short8 kc0 = *(const short8*)(Lk + r*128 + (( lg*16     ) ^ m));
                const short8 kc1 = *(const short8*)(Lk + r*128 + ((64 + lg*16 ) ^ m));
                s[t4] = __builtin_amdgcn_mfma_f32_16x16x32_bf16(kc0, qf[0], z4,    0, 0, 0);
                s[t4] = __builtin_amdgcn_mfma_f32_16x16x32_bf16(kc1, qf[1], s[t4], 0, 0, 0);
            }

            const bool full = (kb + 63 <= qw);
            float x[4][4];
            #pragma unroll
            for (int t4 = 0; t4 < 4; ++t4)
                #pragma unroll
                for (int r = 0; r < 4; ++r) {
                    float v = s[t4][r];
                    if (!full)
                        v = (kb + t4*16 + lg*4 + r <= qw + l16) ? v : -1e30f;
                    x[t4][r] = v;
                }
            float vm0 = fmaxf(fmaxf(x[0][0], x[0][1]), fmaxf(x[0][2], x[0][3]));
            float vm1 = fmaxf(fmaxf(x[1][0], x[1][1]), fmaxf(x[1][2], x[1][3]));
            float vm2 = fmaxf(fmaxf(x[2][0], x[2][1]), fmaxf(x[2][2], x[2][3]));
            float vm3 = fmaxf(fmaxf(x[3][0], x[3][1]), fmaxf(x[3][2], x[3][3]));
            float vm  = fmaxf(fmaxf(vm0, vm1), fmaxf(vm2, vm3));
            vm = fmaxf(vm, __shfl_xor(vm, 16, 64));
            vm = fmaxf(vm, __shfl_xor(vm, 32, 64));
            const float mn = fmaxf(mrow, vm);
            float rs = 0.f;
            #pragma unroll
            for (int t4 = 0; t4 < 4; ++t4)
                #pragma unroll
                for (int r = 0; r < 4; ++r) {
                    const float pe = __builtin_amdgcn_exp2f(x[t4][r] - mn);
                    x[t4][r] = pe;
                    rs += pe;
                }
            rs += __shfl_xor(rs, 16, 64);
            rs += __shfl_xor(rs, 32, 64);
            if (__all(vm <= mrow)) {
                lrow += rs;
            } else {
                const float al = __builtin_amdgcn_exp2f(mrow - mn);
                lrow = lrow*al + rs;
                #pragma unroll
                for (int cb = 0; cb < 4; ++cb)
                    #pragma unroll
                    for (int r = 0; r < 4; ++r)
                        o[cb][r] *= al;
            }
            mrow = mn;

            union { unsigned u[4]; short8 v; } p0, p1;
            p0.u[0] = cvtpk(x[0][0], x[0][1]);
            p0.u[1] = cvtpk(x[0][2], x[0][3]);
            p0.u[2] = cvtpk(x[1][0], x[1][1]);
            p0.u[3] = cvtpk(x[1][2], x[1][3]);
            p1.u[0] = cvtpk(x[2][0], x[2][1]);
            p1.u[1] = cvtpk(x[2][2], x[2][3]);
            p1.u[2] = cvtpk(x[3][0], x[3][1]);
            p1.u[3] = cvtpk(x[3][2], x[3][3]);

            #pragma unroll
            for (int cb = 0; cb < 4; ++cb) {
                const int d = cb*16 + l16;
                const int mv = (d & 7) << 4;
                const char* vb = Lv + d*128;
                union { short8 v; short4v hh[2]; } v0, v1;
                v0.hh[0] = *(const short4v*)(vb + ((lg*8     ) ^ mv));
                v0.hh[1] = *(const short4v*)(vb + ((lg*8 + 32) ^ mv));
                v1.hh[0] = *(const short4v*)(vb + ((lg*8 + 64) ^ mv));
                v1.hh[1] = *(const short4v*)(vb + ((lg*8 + 96) ^ mv));
                o[cb] = __builtin_amdgcn_mfma_f32_16x16x32_bf16(v0.v, p0.v, o[cb], 0, 0, 0);
                o[cb] = __builtin_amdgcn_mfma_f32_16x16x32_bf16(v1.v, p1.v, o[cb], 0, 0, 0);
            }
        }
        __builtin_amdgcn_s_barrier();
    }

    {
        const float inv = 1.0f / lrow;
        const int q = qw + l16;
        ushort* yr = y + ((size_t)b*T_ + q)*C_ + h*D_ + lg*4;
        #pragma unroll
        for (int cb = 0; cb < 4; ++cb) {
            union { unsigned u[2]; short4v v; } st;
            st.u[0] = cvtpk(o[cb][0]*inv, o[cb][1]*inv);
            st.u[1] = cvtpk(o[cb][2]*inv, o[cb][3]*inv);
            *(short4v*)(yr + cb*16) = st.v;
        }
    }
}

extern "C" void kernel_launch(void* const* d_in, const int* in_sizes, int n_in,
                              void* d_out, int out_size, void* d_ws, size_t ws_size,
                              hipStream_t stream)
{
    const float* x      = (const float*)d_in[0];
    const float* W_attn = (const float*)d_in[1];
    const float* b_attn = (const float*)d_in[2];
    const float* W_proj = (const float*)d_in[3];
    const float* b_proj = (const float*)d_in[4];
    const float* bQ     = (const float*)d_in[5];
    const float* bK     = (const float*)d_in[6];
    float* out = (float*)d_out;

    const size_t HE = (size_t)BH_ * T_ * D_;   // 8M elems
    ushort* Qb = (ushort*)d_ws;
    ushort* Kb = Qb + HE;
    ushort* Vt = Kb + HE;
    ushort* y  = Vt + HE;
    ushort* Wpt = (ushort*)d_ws;               // aliases Qb (dead after attn)

    ushort* Xb  = (ushort*)d_out;              // scratch in d_out (dead before GEMM2)
    ushort* Wat = (ushort*)d_out + (size_t)M_ * C_;

    // 1) fused prepass: x->bf16, W_attn^T, bQ tuple copy
    prepass_kernel<<<2817, 256, 0, stream>>>(x, Xb, W_attn, Wat,
                                             bQ, out + (size_t)M_ * C_);

    // 2) QKV GEMM: 256x256 8-phase, 384 blocks (32 m x 12 n, XCD-chunked)
    gemmqkv_kernel<<<384, 512, 0, stream>>>(
        Xb, Wat, b_attn, bQ, bK, Qb, Kb, Vt);

    // 3) causal flash attention
    attn_kernel<<<2048, 256, 0, stream>>>(Qb, Kb, Vt, y);

    // 4) W_proj^T into dead Qb region
    transpose_w_kernel<<<dim3(C_/64, C_/64), 256, 0, stream>>>(W_proj, Wpt, C_, C_);

    // 5) out = y @ W_proj + b_proj (64 x 8, XCD-striped)
    gemm2_kernel<<<512, 256, 0, stream>>>(
        y, Wpt, out, b_proj, C_, C_);
}